// Round 7
// baseline (346.059 us; speedup 1.0000x reference)
//
#include <hip/hip_runtime.h>

#define QLEN 2048
#define BSZ  2
#define NH   12
#define DH   64
#define DM   768
#define HID  2304
#define SCALE 0.125f
#define RELROWS 2176     // 2048 + 128 zero pad (max g used = 2174)
#define PADT 88          // T strip row stride (bf16 elems), 5 cbs = 80 + pad

typedef __attribute__((ext_vector_type(8))) short short8;
typedef __attribute__((ext_vector_type(4))) float f32x4;
typedef __attribute__((ext_vector_type(4))) int i32x4;
typedef unsigned short ushort_t;

static __device__ __forceinline__ ushort_t f2bf(float x) {
  unsigned u = __float_as_uint(x);
  return (ushort_t)((u + 0x7FFFu + ((u >> 16) & 1u)) >> 16);
}
static __device__ __forceinline__ float bf2f(ushort_t h) {
  return __uint_as_float(((unsigned)h) << 16);
}
static __device__ __forceinline__ unsigned cvt_pk_bf16(float lo, float hi) {
  unsigned r;
  asm("v_cvt_pk_bf16_f32 %0, %1, %2" : "=v"(r) : "v"(lo), "v"(hi));
  return r;
}

// ---------------------------------------------------------------------------
// Kernel 1: QKV projection, bf16 MFMA, f32 inputs (pack fused into staging).
// Q part pre-scaled by SCALE.  Outputs bf16 [b][n][i|j][d].
// ---------------------------------------------------------------------------
__global__ __launch_bounds__(256)
void qkv_mfma(const float* __restrict__ A, const float* __restrict__ B,
              ushort_t* __restrict__ Qo, ushort_t* __restrict__ Ko,
              ushort_t* __restrict__ Vo) {
  __shared__ __align__(16) ushort_t As[128*64];
  __shared__ __align__(16) ushort_t Bs[128*64];
  const int bx = blockIdx.x;        // 18 N-tiles
  const int by = blockIdx.y;        // 32 M-tiles
  const int rbase = by*128, cbase = bx*128;
  const int tid = threadIdx.x;
  const int wv = tid>>6, lane = tid&63, lrow = lane>>4, lcol = lane&15;
  const int wr = wv>>1, wc = wv&1;
  const int sr = tid>>3, sc = tid&7;

  f32x4 acc[4][4];
  #pragma unroll
  for (int m = 0; m < 4; ++m)
    #pragma unroll
    for (int nn = 0; nn < 4; ++nn)
      acc[m][nn] = (f32x4){0.f,0.f,0.f,0.f};

  for (int kk = 0; kk < DM; kk += 64) {
    __syncthreads();
    #pragma unroll
    for (int q = 0; q < 4; ++q) {
      const int row = sr + 32*q;
      const float4 a0 = *(const float4*)&A[(size_t)(rbase+row)*DM + kk + sc*8];
      const float4 a1 = *(const float4*)&A[(size_t)(rbase+row)*DM + kk + sc*8 + 4];
      i32x4 va = { (int)cvt_pk_bf16(a0.x,a0.y), (int)cvt_pk_bf16(a0.z,a0.w),
                   (int)cvt_pk_bf16(a1.x,a1.y), (int)cvt_pk_bf16(a1.z,a1.w) };
      *(short8*)((char*)As + row*128 + ((sc*16) ^ ((row&7)<<4))) = __builtin_bit_cast(short8, va);
      const float4 b0 = *(const float4*)&B[(size_t)(cbase+row)*DM + kk + sc*8];
      const float4 b1 = *(const float4*)&B[(size_t)(cbase+row)*DM + kk + sc*8 + 4];
      i32x4 vb = { (int)cvt_pk_bf16(b0.x,b0.y), (int)cvt_pk_bf16(b0.z,b0.w),
                   (int)cvt_pk_bf16(b1.x,b1.y), (int)cvt_pk_bf16(b1.z,b1.w) };
      *(short8*)((char*)Bs + row*128 + ((sc*16) ^ ((row&7)<<4))) = __builtin_bit_cast(short8, vb);
    }
    __syncthreads();
    short8 af[4][2], bfr[4][2];
    #pragma unroll
    for (int m = 0; m < 4; ++m) {
      const int row = wr*64 + m*16 + lcol;
      af[m][0] = *(const short8*)((const char*)As + row*128 + (((     lrow*16)) ^ ((row&7)<<4)));
      af[m][1] = *(const short8*)((const char*)As + row*128 + (((64 + lrow*16)) ^ ((row&7)<<4)));
    }
    #pragma unroll
    for (int nn = 0; nn < 4; ++nn) {
      const int row = wc*64 + nn*16 + lcol;
      bfr[nn][0] = *(const short8*)((const char*)Bs + row*128 + (((     lrow*16)) ^ ((row&7)<<4)));
      bfr[nn][1] = *(const short8*)((const char*)Bs + row*128 + (((64 + lrow*16)) ^ ((row&7)<<4)));
    }
    #pragma unroll
    for (int m = 0; m < 4; ++m)
      #pragma unroll
      for (int nn = 0; nn < 4; ++nn) {
        acc[m][nn] = __builtin_amdgcn_mfma_f32_16x16x32_bf16(af[m][0], bfr[nn][0], acc[m][nn], 0, 0, 0);
        acc[m][nn] = __builtin_amdgcn_mfma_f32_16x16x32_bf16(af[m][1], bfr[nn][1], acc[m][nn], 0, 0, 0);
      }
  }
  const int part = cbase / DM;      // uniform per block
  ushort_t* dst = (part == 0) ? Qo : ((part == 1) ? Ko : Vo);
  const float sc2 = (part == 0) ? SCALE : 1.0f;   // pre-scale Q
  #pragma unroll
  for (int nn = 0; nn < 4; ++nn) {
    const int h  = cbase - part*DM + wc*64 + nn*16;
    const int nh = h >> 6;
    const int d  = (h & 63) + lcol;
    #pragma unroll
    for (int m = 0; m < 4; ++m)
      #pragma unroll
      for (int reg = 0; reg < 4; ++reg) {
        const int r = rbase + wr*64 + m*16 + lrow*4 + reg;
        const int i = r >> 1, b = r & 1;
        dst[((size_t)(b*NH + nh)*QLEN + i)*DH + d] = f2bf(acc[m][nn][reg] * sc2);
      }
  }
}

// ---------------------------------------------------------------------------
// Kernel 2: V bf16 [bn][j][d] -> Vt bf16 [bn][d][j]  (LDS transpose)
// ---------------------------------------------------------------------------
__global__ __launch_bounds__(256)
void vt_pack(const ushort_t* __restrict__ V, ushort_t* __restrict__ Vt) {
  __shared__ ushort_t Ls[64][72];
  const int jt = blockIdx.x, bn = blockIdx.y;
  const int tid = threadIdx.x;
  const size_t base = (size_t)bn * (QLEN*DH);
  #pragma unroll
  for (int q = 0; q < 2; ++q) {
    const int row = (tid>>3) + 32*q;
    const int c8  = (tid&7)*8;
    *(short8*)&Ls[row][c8] = *(const short8*)&V[base + (size_t)(jt*64+row)*DH + c8];
  }
  __syncthreads();
  #pragma unroll
  for (int q = 0; q < 2; ++q) {
    const int d  = (tid>>3) + 32*q;
    const int j8 = (tid&7)*8;
    short8 o;
    #pragma unroll
    for (int e = 0; e < 8; ++e) o[e] = (short)Ls[j8+e][d];
    *(short8*)&Vt[base + (size_t)d*QLEN + jt*64 + j8] = o;
  }
}

// ---------------------------------------------------------------------------
// Kernel 3: pack r_emb -> RELp bf16 [n][g][d] (zero pad); rbias*SCALE -> rbp
// ---------------------------------------------------------------------------
__global__ __launch_bounds__(256)
void rel_pack(const float* __restrict__ remb, const float* __restrict__ rbias,
              ushort_t* __restrict__ RELp, float* __restrict__ rbp) {
  const int n = blockIdx.y;
  const int g = blockIdx.x*4 + (threadIdx.x >> 6);
  const int d = threadIdx.x & 63;
  const bool ok = g < QLEN;
  const float v = ok ? remb[((size_t)g*NH + n)*DH + d] : 0.f;
  RELp[((size_t)n*RELROWS + g)*DH + d] = f2bf(v);
  if (d == 0) rbp[n*RELROWS + g] = (ok ? rbias[g*NH + n] : 0.f) * SCALE;
}

// ---------------------------------------------------------------------------
// Kernel 4: KB[b,n,j] = dot(r_w_bias[n], K[b,n,j,:]) * SCALE
// ---------------------------------------------------------------------------
__global__ __launch_bounds__(256)
void kbias_kernel(const ushort_t* __restrict__ K, const float* __restrict__ rwb,
                  float* __restrict__ KB) {
  const int wv = threadIdx.x >> 6, lane = threadIdx.x & 63;
  const int row = blockIdx.x*4 + wv;             // (b*NH+n)*QLEN + j
  const int n = (row >> 11) % NH;
  float v = bf2f(K[(size_t)row*DH + lane]) * rwb[n*DH + lane];
  #pragma unroll
  for (int o = 32; o > 0; o >>= 1) v += __shfl_xor(v, o, 64);
  if (lane == 0) KB[row] = v * SCALE;
}

// ---------------------------------------------------------------------------
// Kernel 5: MFMA flash attention, cooperative LDS staging + key-chunk split.
// grid = (64 = 32 iq x 2 chunks [heavy-first], 24 bn), block = 256 (4 waves).
// Block covers 64 q-rows (wave wv owns rows iq*64+wv*16..+15) x keys
// [1024c, 1024c+1024) as <=16 tiles of 64 keys.  Per tile: K[64j][64d] and
// Vt[64d][64j] staged coalesced into XOR-swizzled LDS (reg-prefetched one
// tile ahead, T14), barrier, then waves work independently: T strip (REL
// from global, L2-hot) -> wave LDS; swapped S from Ks; in-register softmax
// + P redistribution; PV from Vts.  m init -1e30 so fully-masked tiles
// underflow to p=0.  Writes partial (acc bf16, m/l f32) per (bn,iq,c).
// ---------------------------------------------------------------------------
__global__ __launch_bounds__(256, 4)
void attn_partial(const ushort_t* __restrict__ Qb,
                  const ushort_t* __restrict__ Kb,
                  const ushort_t* __restrict__ Vt,
                  const ushort_t* __restrict__ RELp,
                  const float* __restrict__ rbp,
                  const float* __restrict__ KB,
                  ushort_t* __restrict__ Pacc,
                  float* __restrict__ Pm,
                  float* __restrict__ Pl) {
  __shared__ __align__(16) ushort_t Ks[64*64];     // [j][d], XOR swz
  __shared__ __align__(16) ushort_t Vts[64*64];    // [d][j], XOR swz
  __shared__ __align__(16) ushort_t Tlds[4][16*PADT];
  const int x  = blockIdx.x;
  const int iq = 31 - (x >> 1);
  const int c  = x & 1;
  if (c == 1 && iq < 16) return;
  const int bn = blockIdx.y;
  const int n  = bn % NH;
  const int tid = threadIdx.x;
  const int wv = tid >> 6, lane = tid & 63;
  const int lrow = lane >> 4, lcol = lane & 15;
  const int ib = iq*64;
  const size_t base = (size_t)bn * (QLEN*DH);
  ushort_t* Tw = &Tlds[wv][0];

  const int qi = ib + wv*16 + lcol;
  const short8 qf0 = *(const short8*)&Qb[base + (size_t)qi*DH + lrow*8];
  const short8 qf1 = *(const short8*)&Qb[base + (size_t)qi*DH + 32 + lrow*8];

  f32x4 accO[4];
  float mreg = -1.0e30f, lreg = 0.f;
  #pragma unroll
  for (int r = 0; r < 4; ++r) accO[r] = (f32x4){0.f,0.f,0.f,0.f};

  const int ntiles = min(16, ((ib + 63 - c*1024) >> 6) + 1);
  const int srow = tid >> 3, scol8 = (tid & 7) * 8;
  // prologue: prefetch tile 0 into registers (coalesced)
  short8 kreg[2], vreg[2];
  {
    const int j0n = c*1024;
    #pragma unroll
    for (int p = 0; p < 2; ++p) {
      kreg[p] = *(const short8*)&Kb[base + (size_t)(j0n + srow + 32*p)*DH + scol8];
      vreg[p] = *(const short8*)&Vt[base + (size_t)(srow + 32*p)*QLEN + j0n + scol8];
    }
  }

  for (int tt = 0; tt < ntiles; ++tt) {
    const int j0 = c*1024 + tt*64;
    __syncthreads();                 // prev tile's readers done
    #pragma unroll
    for (int p = 0; p < 2; ++p) {
      const int row = srow + 32*p;
      *(short8*)((char*)Ks  + row*128 + ((scol8*2) ^ ((row&7)<<4))) = kreg[p];
      *(short8*)((char*)Vts + row*128 + ((scol8*2) ^ ((row&7)<<4))) = vreg[p];
    }
    __syncthreads();
    // prefetch next tile (overlaps with compute below)
    {
      const int jn = c*1024 + min(tt+1, ntiles-1)*64;
      #pragma unroll
      for (int p = 0; p < 2; ++p) {
        kreg[p] = *(const short8*)&Kb[base + (size_t)(jn + srow + 32*p)*DH + scol8];
        vreg[p] = *(const short8*)&Vt[base + (size_t)(srow + 32*p)*QLEN + jn + scol8];
      }
    }
    // ---- T strip = Qs*REL^T + rbias (5 col-blocks) -> wave-private LDS ----
    const int gbw = 2032 + j0 - ib - wv*16;            // >= 0
    #pragma unroll
    for (int cb = 0; cb < 5; ++cb) {
      const int g = gbw + cb*16 + lcol;                // <= 2174 < RELROWS
      const size_t ro = ((size_t)n*RELROWS + g)*DH + lrow*8;
      const short8 r0 = *(const short8*)&RELp[ro];
      const short8 r1 = *(const short8*)&RELp[ro + 32];
      f32x4 tt2 = (f32x4){0.f,0.f,0.f,0.f};
      tt2 = __builtin_amdgcn_mfma_f32_16x16x32_bf16(qf0, r0, tt2, 0, 0, 0);
      tt2 = __builtin_amdgcn_mfma_f32_16x16x32_bf16(qf1, r1, tt2, 0, 0, 0);
      const float rb = rbp[n*RELROWS + g];
      #pragma unroll
      for (int reg = 0; reg < 4; ++reg)
        Tw[(lrow*4 + reg)*PADT + cb*16 + lcol] = f2bf(tt2[reg] + rb);
    }
    // ---- S^T = K * Qs^T (swapped) from Ks LDS ----
    f32x4 s[4];
    #pragma unroll
    for (int cb = 0; cb < 4; ++cb) {
      const int krow = cb*16 + lcol;
      const char* kr = (const char*)Ks + krow*128;
      const short8 k0 = *(const short8*)(kr + (((     lrow*16)) ^ ((krow&7)<<4)));
      const short8 k1 = *(const short8*)(kr + (((64 + lrow*16)) ^ ((krow&7)<<4)));
      f32x4 a = (f32x4){0.f,0.f,0.f,0.f};
      a = __builtin_amdgcn_mfma_f32_16x16x32_bf16(k0, qf0, a, 0, 0, 0);
      a = __builtin_amdgcn_mfma_f32_16x16x32_bf16(k1, qf1, a, 0, 0, 0);
      s[cb] = a;
    }
    // ---- + T(diag) + KB, causal mask ----
    const int igq = ib + wv*16 + lcol;
    #pragma unroll
    for (int cb = 0; cb < 4; ++cb) {
      const float4 kb4 = *(const float4*)&KB[bn*QLEN + j0 + cb*16 + lrow*4];
      const float kbr[4] = {kb4.x, kb4.y, kb4.z, kb4.w};
      #pragma unroll
      for (int reg = 0; reg < 4; ++reg) {
        const int kl = cb*16 + lrow*4 + reg;           // key local
        const int tc = 15 + kl - lcol;                 // [0, 78]
        const float sv = s[cb][reg] + bf2f(Tw[lcol*PADT + tc]) + kbr[reg];
        s[cb][reg] = (j0 + kl > igq) ? -3.0e38f : sv;
      }
    }
    // ---- online softmax (state per-lane, q = lcol; reduce via xor 16,32) --
    float mx = s[0][0];
    #pragma unroll
    for (int cb = 0; cb < 4; ++cb)
      #pragma unroll
      for (int reg = 0; reg < 4; ++reg) mx = fmaxf(mx, s[cb][reg]);
    mx = fmaxf(mx, __shfl_xor(mx, 16, 64));
    mx = fmaxf(mx, __shfl_xor(mx, 32, 64));
    const float mn = fmaxf(mreg, mx);
    const float al = __expf(mreg - mn);
    mreg = mn;
    float ps = 0.f;
    #pragma unroll
    for (int cb = 0; cb < 4; ++cb)
      #pragma unroll
      for (int reg = 0; reg < 4; ++reg) {
        const float p = __expf(s[cb][reg] - mn);
        s[cb][reg] = p; ps += p;
      }
    ps += __shfl_xor(ps, 16, 64);
    ps += __shfl_xor(ps, 32, 64);
    lreg = lreg*al + ps;
    // ---- rescale accO (rows q = lrow*4+reg; al lives at q = lcol) ----
    float alq[4];
    #pragma unroll
    for (int reg = 0; reg < 4; ++reg)
      alq[reg] = __shfl(al, (lane & 48) | (lrow*4 + reg), 64);
    #pragma unroll
    for (int cb = 0; cb < 4; ++cb)
      #pragma unroll
      for (int reg = 0; reg < 4; ++reg) accO[cb][reg] *= alq[reg];
    // ---- pack P to bf16 pairs (per-lane, q = lcol) ----
    unsigned pk[4][2];
    #pragma unroll
    for (int cb = 0; cb < 4; ++cb) {
      pk[cb][0] = cvt_pk_bf16(s[cb][0], s[cb][1]);
      pk[cb][1] = cvt_pk_bf16(s[cb][2], s[cb][3]);
    }
    // ---- redistribute to PV A-fragments + MFMA from Vts ----
    const int srcA = ((lrow & 1) << 5) + lcol;
    const int srcB = srcA + 16;
    const bool hi = (lrow >> 1) != 0;
    #pragma unroll
    for (int ks = 0; ks < 2; ++ks) {
      const unsigned wa0 = (unsigned)__shfl((int)pk[2*ks  ][0], srcA, 64);
      const unsigned wb0 = (unsigned)__shfl((int)pk[2*ks+1][0], srcA, 64);
      const unsigned wa1 = (unsigned)__shfl((int)pk[2*ks  ][1], srcA, 64);
      const unsigned wb1 = (unsigned)__shfl((int)pk[2*ks+1][1], srcA, 64);
      const unsigned wa2 = (unsigned)__shfl((int)pk[2*ks  ][0], srcB, 64);
      const unsigned wb2 = (unsigned)__shfl((int)pk[2*ks+1][0], srcB, 64);
      const unsigned wa3 = (unsigned)__shfl((int)pk[2*ks  ][1], srcB, 64);
      const unsigned wb3 = (unsigned)__shfl((int)pk[2*ks+1][1], srcB, 64);
      i32x4 pw = { (int)(hi ? wb0 : wa0), (int)(hi ? wb1 : wa1),
                   (int)(hi ? wb2 : wa2), (int)(hi ? wb3 : wa3) };
      const short8 pa = __builtin_bit_cast(short8, pw);
      #pragma unroll
      for (int cb = 0; cb < 4; ++cb) {
        const int vrow = cb*16 + lcol;                 // d-row of Vts
        const short8 vf = *(const short8*)((const char*)Vts + vrow*128 +
                            (((ks*64 + lrow*16)) ^ ((vrow&7)<<4)));
        accO[cb] = __builtin_amdgcn_mfma_f32_16x16x32_bf16(pa, vf, accO[cb], 0, 0, 0);
      }
    }
  }
  // ---- store partial (wave owns its 16 q-rows for this chunk) ----
  const int slot = (bn*32 + iq)*2 + c;
  #pragma unroll
  for (int reg = 0; reg < 4; ++reg) {
    const int row = wv*16 + lrow*4 + reg;
    #pragma unroll
    for (int cb = 0; cb < 4; ++cb)
      Pacc[(size_t)slot*4096 + row*64 + cb*16 + lcol] = f2bf(accO[cb][reg]);
  }
  if (lrow == 0) {
    Pm[slot*64 + wv*16 + lcol] = mreg;
    Pl[slot*64 + wv*16 + lcol] = lreg;
  }
}

// ---------------------------------------------------------------------------
// Kernel 5b: combine <=2 chunk partials per q-row, normalize, emit bf16 AV.
// ---------------------------------------------------------------------------
__global__ __launch_bounds__(256)
void attn_combine(const ushort_t* __restrict__ Pacc, const float* __restrict__ Pm,
                  const float* __restrict__ Pl, ushort_t* __restrict__ AV) {
  const int iq = blockIdx.x, bn = blockIdx.y;
  const int tid = threadIdx.x;
  const int row = tid >> 2, d0 = (tid & 3) << 4;
  const int slot0 = (bn*32 + iq)*2;
  float acc[16];
  {
    const short8 a0 = *(const short8*)&Pacc[(size_t)slot0*4096 + row*64 + d0];
    const short8 a1 = *(const short8*)&Pacc[(size_t)slot0*4096 + row*64 + d0 + 8];
    #pragma unroll
    for (int e = 0; e < 8; ++e) {
      acc[e]   = bf2f((ushort_t)a0[e]);
      acc[e+8] = bf2f((ushort_t)a1[e]);
    }
  }
  float lv;
  if (iq >= 16) {
    const float m0 = Pm[slot0*64 + row], m1 = Pm[(slot0+1)*64 + row];
    const float l0 = Pl[slot0*64 + row], l1 = Pl[(slot0+1)*64 + row];
    const float ms = fmaxf(m0, m1);
    const float w0 = __expf(m0 - ms), w1 = __expf(m1 - ms);
    lv = l0*w0 + l1*w1;
    const short8 b0 = *(const short8*)&Pacc[(size_t)(slot0+1)*4096 + row*64 + d0];
    const short8 b1 = *(const short8*)&Pacc[(size_t)(slot0+1)*4096 + row*64 + d0 + 8];
    #pragma unroll
    for (int e = 0; e < 8; ++e) {
      acc[e]   = acc[e]*w0   + bf2f((ushort_t)b0[e])*w1;
      acc[e+8] = acc[e+8]*w0 + bf2f((ushort_t)b1[e])*w1;
    }
  } else {
    lv = Pl[slot0*64 + row];
  }
  const float inv = 1.0f / lv;
  const int i = iq*64 + row;
  short8 o0, o1;
  #pragma unroll
  for (int e = 0; e < 8; ++e) {
    o0[e] = (short)f2bf(acc[e]*inv);
    o1[e] = (short)f2bf(acc[e+8]*inv);
  }
  *(short8*)&AV[((size_t)bn*QLEN + i)*DH + d0] = o0;
  *(short8*)&AV[((size_t)bn*QLEN + i)*DH + d0 + 8] = o1;
}

// ---------------------------------------------------------------------------
// Kernel 6: O-projection, bf16 MFMA; B = o_w f32 (pack fused into staging).
// ---------------------------------------------------------------------------
__global__ __launch_bounds__(256)
void oproj_mfma(const ushort_t* __restrict__ AVp, const float* __restrict__ B,
                float* __restrict__ AO) {
  __shared__ __align__(16) ushort_t As[128*64];
  __shared__ __align__(16) ushort_t Bs[128*64];
  const int bx = blockIdx.x;        // 6 N-tiles
  const int by = blockIdx.y;        // 32 M-tiles
  const int rbase = by*128, cbase = bx*128;
  const int tid = threadIdx.x;
  const int wv = tid>>6, lane = tid&63, lrow = lane>>4, lcol = lane&15;
  const int wr = wv>>1, wc = wv&1;
  const int sr = tid>>3, sc = tid&7;

  f32x4 acc[4][4];
  #pragma unroll
  for (int m = 0; m < 4; ++m)
    #pragma unroll
    for (int nn = 0; nn < 4; ++nn)
      acc[m][nn] = (f32x4){0.f,0.f,0.f,0.f};

  for (int kk = 0; kk < DM; kk += 64) {
    const int nh = kk >> 6;         // head index
    __syncthreads();
    #pragma unroll
    for (int q = 0; q < 4; ++q) {
      const int row = sr + 32*q;
      const int r = rbase + row, i = r >> 1, b = r & 1;
      const short8 va = *(const short8*)&AVp[((size_t)(b*NH + nh)*QLEN + i)*DH + sc*8];
      *(short8*)((char*)As + row*128 + ((sc*16) ^ ((row&7)<<4))) = va;
      const float4 b0 = *(const float4*)&B[(size_t)(cbase+row)*DM + kk + sc*8];
      const float4 b1 = *(const float4*)&B[(size_t)(cbase+row)*DM + kk + sc*8 + 4];
      i32x4 vb = { (int)cvt_pk_bf16(b0.x,b0.y), (int)cvt_pk_bf16(b0.z,b0.w),
                   (int)cvt_pk_bf16(b1.x,b1.y), (int)cvt_pk_bf16(b1.z,b1.w) };
      *(short8*)((char*)Bs + row*128 + ((sc*16) ^ ((row&7)<<4))) = __builtin_bit_cast(short8, vb);
    }
    __syncthreads();
    short8 af[4][2], bfr[4][2];
    #pragma unroll
    for (int m = 0; m < 4; ++m) {
      const int row = wr*64 + m*16 + lcol;
      af[m][0] = *(const short8*)((const char*)As + row*128 + (((     lrow*16)) ^ ((row&7)<<4)));
      af[m][1] = *(const short8*)((const char*)As + row*128 + (((64 + lrow*16)) ^ ((row&7)<<4)));
    }
    #pragma unroll
    for (int nn = 0; nn < 4; ++nn) {
      const int row = wc*64 + nn*16 + lcol;
      bfr[nn][0] = *(const short8*)((const char*)Bs + row*128 + (((     lrow*16)) ^ ((row&7)<<4)));
      bfr[nn][1] = *(const short8*)((const char*)Bs + row*128 + (((64 + lrow*16)) ^ ((row&7)<<4)));
    }
    #pragma unroll
    for (int m = 0; m < 4; ++m)
      #pragma unroll
      for (int nn = 0; nn < 4; ++nn) {
        acc[m][nn] = __builtin_amdgcn_mfma_f32_16x16x32_bf16(af[m][0], bfr[nn][0], acc[m][nn], 0, 0, 0);
        acc[m][nn] = __builtin_amdgcn_mfma_f32_16x16x32_bf16(af[m][1], bfr[nn][1], acc[m][nn], 0, 0, 0);
      }
  }
  #pragma unroll
  for (int nn = 0; nn < 4; ++nn) {
    const int mcol = cbase + wc*64 + nn*16 + lcol;
    #pragma unroll
    for (int mi = 0; mi < 4; ++mi)
      #pragma unroll
      for (int reg = 0; reg < 4; ++reg) {
        const int r = rbase + wr*64 + mi*16 + lrow*4 + reg;
        AO[(size_t)r*DM + mcol] = acc[mi][nn][reg];
      }
  }
}

// ---------------------------------------------------------------------------
// Kernel 7: residual + LayerNorm.
// ---------------------------------------------------------------------------
__global__ __launch_bounds__(256)
void ln_kernel(const float* __restrict__ AO, const float* __restrict__ W,
               const float* __restrict__ gamma, const float* __restrict__ beta,
               float* __restrict__ out) {
  const int r = blockIdx.x;
  const int tid = threadIdx.x;
  const int wv = tid >> 6, lane = tid & 63;
  float x[3];
  #pragma unroll
  for (int q = 0; q < 3; ++q) {
    const int mcol = tid + q*256;
    x[q] = AO[(size_t)r*DM + mcol] + W[(size_t)r*DM + mcol];
  }
  float s1 = x[0] + x[1] + x[2];
  float s2 = x[0]*x[0] + x[1]*x[1] + x[2]*x[2];
  #pragma unroll
  for (int o = 32; o > 0; o >>= 1) { s1 += __shfl_xor(s1, o, 64); s2 += __shfl_xor(s2, o, 64); }
  __shared__ float a1[4], a2[4];
  if (lane == 0) { a1[wv] = s1; a2[wv] = s2; }
  __syncthreads();
  s1 = a1[0] + a1[1] + a1[2] + a1[3];
  s2 = a2[0] + a2[1] + a2[2] + a2[3];
  const float mu  = s1 * (1.0f/DM);
  const float var = s2 * (1.0f/DM) - mu*mu;
  const float rs  = rsqrtf(var + 1e-5f);
  #pragma unroll
  for (int q = 0; q < 3; ++q) {
    const int mcol = tid + q*256;
    out[(size_t)r*DM + mcol] = (x[q] - mu)*rs*gamma[mcol] + beta[mcol];
  }
}

// ---------------------------------------------------------------------------
extern "C" void kernel_launch(void* const* d_in, const int* in_sizes, int n_in,
                              void* d_out, int out_size, void* d_ws, size_t ws_size,
                              hipStream_t stream) {
  const float* w      = (const float*)d_in[0];
  const float* r_emb  = (const float*)d_in[1];
  const float* r_wb   = (const float*)d_in[2];
  const float* r_bias = (const float*)d_in[3];
  const float* qkv_w  = (const float*)d_in[4];
  const float* o_w    = (const float*)d_in[5];
  const float* ln_g   = (const float*)d_in[6];
  const float* ln_b   = (const float*)d_in[7];
  float* out = (float*)d_out;

  const size_t QS = (size_t)BSZ*NH*QLEN*DH;       // 3,145,728 elems
  ushort_t* u     = (ushort_t*)d_ws;
  ushort_t* Vb16  = u;                            // QS (dead after vt_pack)
  ushort_t* AVb16 = Vb16;                         // overlay: written by combine
  ushort_t* Qb    = u + QS;
  ushort_t* Kb    = Qb + QS;
  ushort_t* Vt    = Kb + QS;
  ushort_t* RELp  = Vt + QS;                      // NH*RELROWS*DH
  float* rbp = (float*)(RELp + (size_t)NH*RELROWS*DH);
  float* KBb = rbp + NH*RELROWS;                  // 49152 f32
  float* Pmb = KBb + (size_t)BSZ*NH*QLEN;         // 1536*64 f32
  float* Plb = Pmb + 1536*64;                     // 1536*64 f32
  ushort_t* Pacc = (ushort_t*)(Plb + 1536*64);    // 1536*4096 bf16 (12.6 MB)
  float* AO  = (float*)Qb;                        // overlays Qb+Kb (dead by oproj)

  qkv_mfma<<<dim3(HID/128, (QLEN*BSZ)/128), dim3(256), 0, stream>>>(w, qkv_w, Qb, Kb, Vb16);
  vt_pack<<<dim3(QLEN/64, BSZ*NH), dim3(256), 0, stream>>>(Vb16, Vt);
  rel_pack<<<dim3(RELROWS/4, NH), dim3(256), 0, stream>>>(r_emb, r_bias, RELp, rbp);
  kbias_kernel<<<dim3(BSZ*NH*QLEN/4), dim3(256), 0, stream>>>(Kb, r_wb, KBb);
  attn_partial<<<dim3(64, BSZ*NH), dim3(256), 0, stream>>>(Qb, Kb, Vt, RELp, rbp, KBb, Pacc, Pmb, Plb);
  attn_combine<<<dim3(32, BSZ*NH), dim3(256), 0, stream>>>(Pacc, Pmb, Plb, AVb16);
  oproj_mfma<<<dim3(DM/128, (QLEN*BSZ)/128), dim3(256), 0, stream>>>(AVb16, o_w, AO);
  ln_kernel<<<dim3(QLEN*BSZ), dim3(256), 0, stream>>>(AO, w, ln_g, ln_b, out);
}

// Round 8
// 247.686 us; speedup vs baseline: 1.3972x; 1.3972x over previous
//
#include <hip/hip_runtime.h>

#define QLEN 2048
#define BSZ  2
#define NH   12
#define DH   64
#define DM   768
#define HID  2304
#define SCALE 0.125f
#define RELROWS 2176     // 2048 + 128 zero pad; 136 strips of 16
#define PADT2 152        // T strip row stride (bf16), 9 cbs = 144 + pad

typedef __attribute__((ext_vector_type(8))) short short8;
typedef __attribute__((ext_vector_type(4))) float f32x4;
typedef __attribute__((ext_vector_type(4))) int i32x4;
typedef unsigned short ushort_t;

static __device__ __forceinline__ ushort_t f2bf(float x) {
  unsigned u = __float_as_uint(x);
  return (ushort_t)((u + 0x7FFFu + ((u >> 16) & 1u)) >> 16);
}
static __device__ __forceinline__ float bf2f(ushort_t h) {
  return __uint_as_float(((unsigned)h) << 16);
}
static __device__ __forceinline__ unsigned cvt_pk_bf16(float lo, float hi) {
  unsigned r;
  asm("v_cvt_pk_bf16_f32 %0, %1, %2" : "=v"(r) : "v"(lo), "v"(hi));
  return r;
}

// Fragment-order layouts: one wave-load (64 lanes x 16B) = one MFMA operand.
// A/B frag: lane l holds rows/cols (l&15) of a 16-strip, k = (l>>4)*8 + e (+32*half).
static __device__ __forceinline__ size_t kf_off(int bn, int j, int d) {   // Kf & Qf
  return ((size_t)((bn*128 + (j>>4))*2 + (d>>5)))*512 + (((d&31)>>3)*16 + (j&15))*8 + (d&7);
}
static __device__ __forceinline__ size_t vtf_off(int bn, int d, int j) {  // Vtf
  return ((size_t)((bn*4 + (d>>4))*64 + (j>>5)))*512 + (((j&31)>>3)*16 + (d&15))*8 + (j&7);
}
static __device__ __forceinline__ size_t relf_off(int n, int g, int d) {  // RELf
  return ((size_t)((n*136 + (g>>4))*2 + (d>>5)))*512 + (((d&31)>>3)*16 + (g&15))*8 + (d&7);
}

// ---------------------------------------------------------------------------
// Kernel 1: QKV projection, bf16 MFMA, f32 inputs.  Q (pre-scaled) and K are
// scattered into FRAGMENT layout (Qf/Kf); V into row layout for vt_pack.
// ---------------------------------------------------------------------------
__global__ __launch_bounds__(256)
void qkv_mfma(const float* __restrict__ A, const float* __restrict__ B,
              ushort_t* __restrict__ Qf, ushort_t* __restrict__ Kf,
              ushort_t* __restrict__ Vo) {
  __shared__ __align__(16) ushort_t As[128*64];
  __shared__ __align__(16) ushort_t Bs[128*64];
  const int bx = blockIdx.x;        // 18 N-tiles
  const int by = blockIdx.y;        // 32 M-tiles
  const int rbase = by*128, cbase = bx*128;
  const int tid = threadIdx.x;
  const int wv = tid>>6, lane = tid&63, lrow = lane>>4, lcol = lane&15;
  const int wr = wv>>1, wc = wv&1;
  const int sr = tid>>3, sc = tid&7;

  f32x4 acc[4][4];
  #pragma unroll
  for (int m = 0; m < 4; ++m)
    #pragma unroll
    for (int nn = 0; nn < 4; ++nn)
      acc[m][nn] = (f32x4){0.f,0.f,0.f,0.f};

  for (int kk = 0; kk < DM; kk += 64) {
    __syncthreads();
    #pragma unroll
    for (int q = 0; q < 4; ++q) {
      const int row = sr + 32*q;
      const float4 a0 = *(const float4*)&A[(size_t)(rbase+row)*DM + kk + sc*8];
      const float4 a1 = *(const float4*)&A[(size_t)(rbase+row)*DM + kk + sc*8 + 4];
      i32x4 va = { (int)cvt_pk_bf16(a0.x,a0.y), (int)cvt_pk_bf16(a0.z,a0.w),
                   (int)cvt_pk_bf16(a1.x,a1.y), (int)cvt_pk_bf16(a1.z,a1.w) };
      *(short8*)((char*)As + row*128 + ((sc*16) ^ ((row&7)<<4))) = __builtin_bit_cast(short8, va);
      const float4 b0 = *(const float4*)&B[(size_t)(cbase+row)*DM + kk + sc*8];
      const float4 b1 = *(const float4*)&B[(size_t)(cbase+row)*DM + kk + sc*8 + 4];
      i32x4 vb = { (int)cvt_pk_bf16(b0.x,b0.y), (int)cvt_pk_bf16(b0.z,b0.w),
                   (int)cvt_pk_bf16(b1.x,b1.y), (int)cvt_pk_bf16(b1.z,b1.w) };
      *(short8*)((char*)Bs + row*128 + ((sc*16) ^ ((row&7)<<4))) = __builtin_bit_cast(short8, vb);
    }
    __syncthreads();
    short8 af[4][2], bfr[4][2];
    #pragma unroll
    for (int m = 0; m < 4; ++m) {
      const int row = wr*64 + m*16 + lcol;
      af[m][0] = *(const short8*)((const char*)As + row*128 + (((     lrow*16)) ^ ((row&7)<<4)));
      af[m][1] = *(const short8*)((const char*)As + row*128 + (((64 + lrow*16)) ^ ((row&7)<<4)));
    }
    #pragma unroll
    for (int nn = 0; nn < 4; ++nn) {
      const int row = wc*64 + nn*16 + lcol;
      bfr[nn][0] = *(const short8*)((const char*)Bs + row*128 + (((     lrow*16)) ^ ((row&7)<<4)));
      bfr[nn][1] = *(const short8*)((const char*)Bs + row*128 + (((64 + lrow*16)) ^ ((row&7)<<4)));
    }
    #pragma unroll
    for (int m = 0; m < 4; ++m)
      #pragma unroll
      for (int nn = 0; nn < 4; ++nn) {
        acc[m][nn] = __builtin_amdgcn_mfma_f32_16x16x32_bf16(af[m][0], bfr[nn][0], acc[m][nn], 0, 0, 0);
        acc[m][nn] = __builtin_amdgcn_mfma_f32_16x16x32_bf16(af[m][1], bfr[nn][1], acc[m][nn], 0, 0, 0);
      }
  }
  const int part = cbase / DM;      // uniform per block
  const float sc2 = (part == 0) ? SCALE : 1.0f;
  #pragma unroll
  for (int nn = 0; nn < 4; ++nn) {
    const int h  = cbase - part*DM + wc*64 + nn*16;
    const int nh = h >> 6;
    const int d  = (h & 63) + lcol;
    #pragma unroll
    for (int m = 0; m < 4; ++m)
      #pragma unroll
      for (int reg = 0; reg < 4; ++reg) {
        const int r = rbase + wr*64 + m*16 + lrow*4 + reg;
        const int i = r >> 1, b = r & 1;
        const int bn = b*NH + nh;
        const ushort_t val = f2bf(acc[m][nn][reg] * sc2);
        if (part == 0)      Qf[kf_off(bn, i, d)] = val;
        else if (part == 1) Kf[kf_off(bn, i, d)] = val;
        else                Vo[((size_t)bn*QLEN + i)*DH + d] = val;
      }
  }
}

// ---------------------------------------------------------------------------
// Kernel 2: V bf16 [bn][j][d] -> Vtf fragment layout (LDS transpose)
// ---------------------------------------------------------------------------
__global__ __launch_bounds__(256)
void vt_pack(const ushort_t* __restrict__ V, ushort_t* __restrict__ Vtf) {
  __shared__ ushort_t Ls[64][72];
  const int jt = blockIdx.x, bn = blockIdx.y;
  const int tid = threadIdx.x;
  const size_t base = (size_t)bn * (QLEN*DH);
  #pragma unroll
  for (int q = 0; q < 2; ++q) {
    const int row = (tid>>3) + 32*q;
    const int c8  = (tid&7)*8;
    *(short8*)&Ls[row][c8] = *(const short8*)&V[base + (size_t)(jt*64+row)*DH + c8];
  }
  __syncthreads();
  #pragma unroll
  for (int h = 0; h < 2; ++h) {
    const int unit = tid + h*256;           // [0,512): (dstrip, jblk, lane)
    const int ds = unit >> 7;               // 0..3
    const int jb = (unit >> 6) & 1;         // 0..1
    const int l  = unit & 63;
    const int dl = ds*16 + (l & 15);
    const int jl = jb*32 + (l >> 4)*8;
    short8 o;
    #pragma unroll
    for (int e = 0; e < 8; ++e) o[e] = (short)Ls[jl + e][dl];
    *(short8*)&Vtf[((size_t)((bn*4 + ds)*64 + jt*2 + jb))*512 + l*8] = o;
  }
}

// ---------------------------------------------------------------------------
// Kernel 3: r_emb -> RELf fragment layout (zero pad); rbias*SCALE -> rbp
// ---------------------------------------------------------------------------
__global__ __launch_bounds__(256)
void rel_pack(const float* __restrict__ remb, const float* __restrict__ rbias,
              ushort_t* __restrict__ RELf, float* __restrict__ rbp) {
  const int n = blockIdx.y;
  const int g = blockIdx.x*4 + (threadIdx.x >> 6);
  const int d = threadIdx.x & 63;
  const bool ok = g < QLEN;
  const float v = ok ? remb[((size_t)g*NH + n)*DH + d] : 0.f;
  RELf[relf_off(n, g, d)] = f2bf(v);
  if (d == 0) rbp[n*RELROWS + g] = (ok ? rbias[g*NH + n] : 0.f) * SCALE;
}

// ---------------------------------------------------------------------------
// Kernel 4: KB[b,n,j] = dot(r_w_bias[n], K[b,n,j,:]) * SCALE  (gather from Kf)
// ---------------------------------------------------------------------------
__global__ __launch_bounds__(256)
void kbias_kernel(const ushort_t* __restrict__ Kf, const float* __restrict__ rwb,
                  float* __restrict__ KB) {
  const int wv = threadIdx.x >> 6, lane = threadIdx.x & 63;
  const int row = blockIdx.x*4 + wv;             // (b*NH+n)*QLEN + j
  const int bn = row >> 11, j = row & (QLEN-1);
  const int n = bn % NH;
  float v = bf2f(Kf[kf_off(bn, j, lane)]) * rwb[n*DH + lane];
  #pragma unroll
  for (int o = 32; o > 0; o >>= 1) v += __shfl_xor(v, o, 64);
  if (lane == 0) KB[row] = v * SCALE;
}

// ---------------------------------------------------------------------------
// Kernel 5: MFMA flash attention, fragment-layout operands (all coalesced).
// Flat grid 3072, XCD-swizzled so each XCD owns 3 consecutive bn (L2 locality).
// Block = 512 thr (8 waves), 16 q-rows; wave w handles 128-key tiles t = w,
// w+8 (NT = it16/8+1 <= 16 => <=2 iters).  Swapped S & swapped PV (O^T) —
// softmax state per-lane (q=lcol), rescale lane-local, P redistributed to
// B-fragments via shfl (no P LDS).  T strip in wave-private LDS.  Cross-wave
// merge of (m,l,accO^T) in LDS (also performs the O^T -> O transpose).
// ---------------------------------------------------------------------------
#define TW_BYTES (16*PADT2*2)          // 4864 per wave
#define SMEM_A   (8*TW_BYTES)          // 38912; merge overlay 128*68*4+1024 fits

__global__ __launch_bounds__(512, 6)
void attn_kernel(const ushort_t* __restrict__ Qf,
                 const ushort_t* __restrict__ Kf,
                 const ushort_t* __restrict__ Vtf,
                 const ushort_t* __restrict__ RELf,
                 const float* __restrict__ rbp,
                 const float* __restrict__ KB,
                 ushort_t* __restrict__ AV) {
  __shared__ __align__(16) char smem[SMEM_A];
  const int f    = blockIdx.x;
  const int wu   = (f & 7)*384 + (f >> 3);     // XCD k -> bn in [3k, 3k+3)
  const int bn   = wu >> 7;
  const int it16 = 127 - (wu & 127);           // heavy tiles first within bn
  const int n    = bn % NH;
  const int tid  = threadIdx.x;
  const int wv = tid >> 6, lane = tid & 63;
  const int lrow = lane >> 4, lcol = lane & 15;
  const int ib = it16*16;
  ushort_t* Tw = (ushort_t*)(smem + wv*TW_BYTES);

  // Q A-fragment: one coalesced pair of wave-loads
  const size_t qo = ((size_t)((bn*128 + it16)*2))*512 + lane*8;
  const short8 qf0 = *(const short8*)&Qf[qo];
  const short8 qf1 = *(const short8*)&Qf[qo + 512];

  f32x4 accO[4];                 // O^T: accO[cb][reg] = O[q=lcol][d=cb*16+lrow*4+reg]
  float mreg = -1.0e30f, lreg = 0.f;
  #pragma unroll
  for (int r = 0; r < 4; ++r) accO[r] = (f32x4){0.f,0.f,0.f,0.f};

  const int NT = (it16 >> 3) + 1;
  for (int t = wv; t < NT; t += 8) {
    const int j0 = t*128;
    const int gbase = 2032 + j0 - ib;          // = 0 (mod 16), in [0, 2032]
    const int gs = gbase >> 4;
    // ---- T strip = Qs*REL^T + rbias (9 cbs, coalesced frag loads) ----
    #pragma unroll
    for (int cb = 0; cb < 9; ++cb) {
      const size_t ro = ((size_t)((n*136 + gs + cb)*2))*512 + lane*8;
      const short8 r0 = *(const short8*)&RELf[ro];
      const short8 r1 = *(const short8*)&RELf[ro + 512];
      f32x4 tt = (f32x4){0.f,0.f,0.f,0.f};
      tt = __builtin_amdgcn_mfma_f32_16x16x32_bf16(qf0, r0, tt, 0, 0, 0);
      tt = __builtin_amdgcn_mfma_f32_16x16x32_bf16(qf1, r1, tt, 0, 0, 0);
      const float rb = rbp[n*RELROWS + gbase + cb*16 + lcol];
      #pragma unroll
      for (int reg = 0; reg < 4; ++reg)       // T[q=lrow*4+reg][relcol=cb*16+lcol]
        Tw[(lrow*4 + reg)*PADT2 + cb*16 + lcol] = f2bf(tt[reg] + rb);
    }
    // ---- S^T = K * Qs^T (8 cbs = 128 keys, coalesced frag loads) ----
    f32x4 s[8];
    #pragma unroll
    for (int cb = 0; cb < 8; ++cb) {
      const size_t ko = ((size_t)((bn*128 + (j0>>4) + cb)*2))*512 + lane*8;
      const short8 k0 = *(const short8*)&Kf[ko];
      const short8 k1 = *(const short8*)&Kf[ko + 512];
      f32x4 a = (f32x4){0.f,0.f,0.f,0.f};
      a = __builtin_amdgcn_mfma_f32_16x16x32_bf16(k0, qf0, a, 0, 0, 0);
      a = __builtin_amdgcn_mfma_f32_16x16x32_bf16(k1, qf1, a, 0, 0, 0);
      s[cb] = a;                               // S^T[key=cb*16+lrow*4+reg][q=lcol]
    }
    // ---- + T(diag) + KB, causal mask ----
    #pragma unroll
    for (int cb = 0; cb < 8; ++cb) {
      const float4 kb4 = *(const float4*)&KB[bn*QLEN + j0 + cb*16 + lrow*4];
      const float kbr[4] = {kb4.x, kb4.y, kb4.z, kb4.w};
      #pragma unroll
      for (int reg = 0; reg < 4; ++reg) {
        const int kl = cb*16 + lrow*4 + reg;
        const int tc = 15 + kl - lcol;         // [0, 142]
        const float sv = s[cb][reg] + bf2f(Tw[lcol*PADT2 + tc]) + kbr[reg];
        s[cb][reg] = (j0 + kl > ib + lcol) ? -3.0e38f : sv;
      }
    }
    // ---- online softmax (per-q via xor 16/32 over 4 lrow lanes) ----
    float mx = s[0][0];
    #pragma unroll
    for (int cb = 0; cb < 8; ++cb)
      #pragma unroll
      for (int reg = 0; reg < 4; ++reg) mx = fmaxf(mx, s[cb][reg]);
    mx = fmaxf(mx, __shfl_xor(mx, 16, 64));
    mx = fmaxf(mx, __shfl_xor(mx, 32, 64));
    const float mn = fmaxf(mreg, mx);
    const float al = __expf(mreg - mn);
    mreg = mn;
    float ps = 0.f;
    unsigned pk[8][2];
    #pragma unroll
    for (int cb = 0; cb < 8; ++cb) {
      float p0 = __expf(s[cb][0] - mn), p1 = __expf(s[cb][1] - mn);
      float p2 = __expf(s[cb][2] - mn), p3 = __expf(s[cb][3] - mn);
      ps += (p0 + p1) + (p2 + p3);
      pk[cb][0] = cvt_pk_bf16(p0, p1);
      pk[cb][1] = cvt_pk_bf16(p2, p3);
    }
    ps += __shfl_xor(ps, 16, 64);
    ps += __shfl_xor(ps, 32, 64);
    lreg = lreg*al + ps;
    #pragma unroll
    for (int cb = 0; cb < 4; ++cb)            // O^T rescale: al is lane-local (q=lcol)
      #pragma unroll
      for (int reg = 0; reg < 4; ++reg) accO[cb][reg] *= al;
    // ---- P^T B-fragments via shfl; O^T += V^T * P^T ----
    const int srcA = ((lrow & 1) << 5) + lcol;
    const int srcB = srcA + 16;
    const bool hi2 = (lrow >> 1) != 0;
    #pragma unroll
    for (int ks = 0; ks < 4; ++ks) {
      const unsigned a0 = (unsigned)__shfl((int)pk[2*ks  ][0], srcA, 64);
      const unsigned b0 = (unsigned)__shfl((int)pk[2*ks+1][0], srcA, 64);
      const unsigned a1 = (unsigned)__shfl((int)pk[2*ks  ][1], srcA, 64);
      const unsigned b1 = (unsigned)__shfl((int)pk[2*ks+1][1], srcA, 64);
      const unsigned a2 = (unsigned)__shfl((int)pk[2*ks  ][0], srcB, 64);
      const unsigned b2 = (unsigned)__shfl((int)pk[2*ks+1][0], srcB, 64);
      const unsigned a3 = (unsigned)__shfl((int)pk[2*ks  ][1], srcB, 64);
      const unsigned b3 = (unsigned)__shfl((int)pk[2*ks+1][1], srcB, 64);
      i32x4 pw = { (int)(hi2 ? b0 : a0), (int)(hi2 ? b1 : a1),
                   (int)(hi2 ? b2 : a2), (int)(hi2 ? b3 : a3) };
      const short8 pb = __builtin_bit_cast(short8, pw);
      #pragma unroll
      for (int cb = 0; cb < 4; ++cb) {
        const short8 vf = *(const short8*)&Vtf[((size_t)((bn*4 + cb)*64 + t*4 + ks))*512 + lane*8];
        accO[cb] = __builtin_amdgcn_mfma_f32_16x16x32_bf16(vf, pb, accO[cb], 0, 0, 0);
      }
    }
  }
  // ---- cross-wave merge in LDS (handles O^T -> O transpose) ----
  __syncthreads();
  float* Macc = (float*)smem;                        // [128][68]: row = wv*16 + q
  float* Mm   = (float*)(smem + 128*68*4);           // [128]
  float* Ml   = Mm + 128;
  #pragma unroll
  for (int cb = 0; cb < 4; ++cb)
    #pragma unroll
    for (int reg = 0; reg < 4; ++reg)
      Macc[(wv*16 + lcol)*68 + cb*16 + lrow*4 + reg] = accO[cb][reg];
  if (lrow == 0) { Mm[wv*16 + lcol] = mreg; Ml[wv*16 + lcol] = lreg; }
  __syncthreads();
  #pragma unroll
  for (int h = 0; h < 2; ++h) {
    const int o = tid + h*512;
    const int row = o >> 6, col = o & 63;            // q-row 0..15, d 0..63
    float M = Mm[row];
    #pragma unroll
    for (int w2 = 1; w2 < 8; ++w2) M = fmaxf(M, Mm[w2*16 + row]);
    float L = 0.f, V = 0.f;
    #pragma unroll
    for (int w2 = 0; w2 < 8; ++w2) {
      const float e = __expf(Mm[w2*16 + row] - M);
      L += Ml[w2*16 + row] * e;
      V += Macc[(w2*16 + row)*68 + col] * e;
    }
    AV[((size_t)bn*QLEN + ib + row)*DH + col] = f2bf(V / L);
  }
}

// ---------------------------------------------------------------------------
// Kernel 6: O-projection, bf16 MFMA; B = o_w f32 (pack fused into staging).
// ---------------------------------------------------------------------------
__global__ __launch_bounds__(256)
void oproj_mfma(const ushort_t* __restrict__ AVp, const float* __restrict__ B,
                float* __restrict__ AO) {
  __shared__ __align__(16) ushort_t As[128*64];
  __shared__ __align__(16) ushort_t Bs[128*64];
  const int bx = blockIdx.x;        // 6 N-tiles
  const int by = blockIdx.y;        // 32 M-tiles
  const int rbase = by*128, cbase = bx*128;
  const int tid = threadIdx.x;
  const int wv = tid>>6, lane = tid&63, lrow = lane>>4, lcol = lane&15;
  const int wr = wv>>1, wc = wv&1;
  const int sr = tid>>3, sc = tid&7;

  f32x4 acc[4][4];
  #pragma unroll
  for (int m = 0; m < 4; ++m)
    #pragma unroll
    for (int nn = 0; nn < 4; ++nn)
      acc[m][nn] = (f32x4){0.f,0.f,0.f,0.f};

  for (int kk = 0; kk < DM; kk += 64) {
    const int nh = kk >> 6;         // head index
    __syncthreads();
    #pragma unroll
    for (int q = 0; q < 4; ++q) {
      const int row = sr + 32*q;
      const int r = rbase + row, i = r >> 1, b = r & 1;
      const short8 va = *(const short8*)&AVp[((size_t)(b*NH + nh)*QLEN + i)*DH + sc*8];
      *(short8*)((char*)As + row*128 + ((sc*16) ^ ((row&7)<<4))) = va;
      const float4 b0 = *(const float4*)&B[(size_t)(cbase+row)*DM + kk + sc*8];
      const float4 b1 = *(const float4*)&B[(size_t)(cbase+row)*DM + kk + sc*8 + 4];
      i32x4 vb = { (int)cvt_pk_bf16(b0.x,b0.y), (int)cvt_pk_bf16(b0.z,b0.w),
                   (int)cvt_pk_bf16(b1.x,b1.y), (int)cvt_pk_bf16(b1.z,b1.w) };
      *(short8*)((char*)Bs + row*128 + ((sc*16) ^ ((row&7)<<4))) = __builtin_bit_cast(short8, vb);
    }
    __syncthreads();
    short8 af[4][2], bfr[4][2];
    #pragma unroll
    for (int m = 0; m < 4; ++m) {
      const int row = wr*64 + m*16 + lcol;
      af[m][0] = *(const short8*)((const char*)As + row*128 + (((     lrow*16)) ^ ((row&7)<<4)));
      af[m][1] = *(const short8*)((const char*)As + row*128 + (((64 + lrow*16)) ^ ((row&7)<<4)));
    }
    #pragma unroll
    for (int nn = 0; nn < 4; ++nn) {
      const int row = wc*64 + nn*16 + lcol;
      bfr[nn][0] = *(const short8*)((const char*)Bs + row*128 + (((     lrow*16)) ^ ((row&7)<<4)));
      bfr[nn][1] = *(const short8*)((const char*)Bs + row*128 + (((64 + lrow*16)) ^ ((row&7)<<4)));
    }
    #pragma unroll
    for (int m = 0; m < 4; ++m)
      #pragma unroll
      for (int nn = 0; nn < 4; ++nn) {
        acc[m][nn] = __builtin_amdgcn_mfma_f32_16x16x32_bf16(af[m][0], bfr[nn][0], acc[m][nn], 0, 0, 0);
        acc[m][nn] = __builtin_amdgcn_mfma_f32_16x16x32_bf16(af[m][1], bfr[nn][1], acc[m][nn], 0, 0, 0);
      }
  }
  #pragma unroll
  for (int nn = 0; nn < 4; ++nn) {
    const int mcol = cbase + wc*64 + nn*16 + lcol;
    #pragma unroll
    for (int mi = 0; mi < 4; ++mi)
      #pragma unroll
      for (int reg = 0; reg < 4; ++reg) {
        const int r = rbase + wr*64 + mi*16 + lrow*4 + reg;
        AO[(size_t)r*DM + mcol] = acc[mi][nn][reg];
      }
  }
}

// ---------------------------------------------------------------------------
// Kernel 7: residual + LayerNorm.
// ---------------------------------------------------------------------------
__global__ __launch_bounds__(256)
void ln_kernel(const float* __restrict__ AO, const float* __restrict__ W,
               const float* __restrict__ gamma, const float* __restrict__ beta,
               float* __restrict__ out) {
  const int r = blockIdx.x;
  const int tid = threadIdx.x;
  const int wv = tid >> 6, lane = tid & 63;
  float x[3];
  #pragma unroll
  for (int q = 0; q < 3; ++q) {
    const int mcol = tid + q*256;
    x[q] = AO[(size_t)r*DM + mcol] + W[(size_t)r*DM + mcol];
  }
  float s1 = x[0] + x[1] + x[2];
  float s2 = x[0]*x[0] + x[1]*x[1] + x[2]*x[2];
  #pragma unroll
  for (int o = 32; o > 0; o >>= 1) { s1 += __shfl_xor(s1, o, 64); s2 += __shfl_xor(s2, o, 64); }
  __shared__ float a1[4], a2[4];
  if (lane == 0) { a1[wv] = s1; a2[wv] = s2; }
  __syncthreads();
  s1 = a1[0] + a1[1] + a1[2] + a1[3];
  s2 = a2[0] + a2[1] + a2[2] + a2[3];
  const float mu  = s1 * (1.0f/DM);
  const float var = s2 * (1.0f/DM) - mu*mu;
  const float rs  = rsqrtf(var + 1e-5f);
  #pragma unroll
  for (int q = 0; q < 3; ++q) {
    const int mcol = tid + q*256;
    out[(size_t)r*DM + mcol] = (x[q] - mu)*rs*gamma[mcol] + beta[mcol];
  }
}

// ---------------------------------------------------------------------------
extern "C" void kernel_launch(void* const* d_in, const int* in_sizes, int n_in,
                              void* d_out, int out_size, void* d_ws, size_t ws_size,
                              hipStream_t stream) {
  const float* w      = (const float*)d_in[0];
  const float* r_emb  = (const float*)d_in[1];
  const float* r_wb   = (const float*)d_in[2];
  const float* r_bias = (const float*)d_in[3];
  const float* qkv_w  = (const float*)d_in[4];
  const float* o_w    = (const float*)d_in[5];
  const float* ln_g   = (const float*)d_in[6];
  const float* ln_b   = (const float*)d_in[7];
  float* out = (float*)d_out;

  const size_t QS = (size_t)BSZ*NH*QLEN*DH;       // 3,145,728 elems
  ushort_t* u     = (ushort_t*)d_ws;
  ushort_t* Vb16  = u;                            // QS (dead after vt_pack)
  ushort_t* AVb16 = Vb16;                         // overlay: written by attn
  ushort_t* Qfb   = u + QS;
  ushort_t* Kfb   = Qfb + QS;
  ushort_t* Vtf   = Kfb + QS;
  ushort_t* RELf  = Vtf + QS;                     // NH*RELROWS*DH
  float* rbp = (float*)(RELf + (size_t)NH*RELROWS*DH);
  float* KBb = rbp + NH*RELROWS;                  // 49152 f32
  float* AO  = (float*)Qfb;                       // overlays Qf+Kf (dead by oproj)

  qkv_mfma<<<dim3(HID/128, (QLEN*BSZ)/128), dim3(256), 0, stream>>>(w, qkv_w, Qfb, Kfb, Vb16);
  vt_pack<<<dim3(QLEN/64, BSZ*NH), dim3(256), 0, stream>>>(Vb16, Vtf);
  rel_pack<<<dim3(RELROWS/4, NH), dim3(256), 0, stream>>>(r_emb, r_bias, RELf, rbp);
  kbias_kernel<<<dim3(BSZ*NH*QLEN/4), dim3(256), 0, stream>>>(Kfb, r_wb, KBb);
  attn_kernel<<<dim3(3072), dim3(512), 0, stream>>>(Qfb, Kfb, Vtf, RELf, rbp, KBb, AVb16);
  oproj_mfma<<<dim3(DM/128, (QLEN*BSZ)/128), dim3(256), 0, stream>>>(AVb16, o_w, AO);
  ln_kernel<<<dim3(QLEN*BSZ), dim3(256), 0, stream>>>(AO, w, ln_g, ln_b, out);
}

// Round 10
// 212.984 us; speedup vs baseline: 1.6248x; 1.1629x over previous
//
#include <hip/hip_runtime.h>

#define QLEN 2048
#define BSZ  2
#define NH   12
#define DH   64
#define DM   768
#define HID  2304
#define SCALE 0.125f
#define RELROWS 2176     // 2048 + 128 zero pad; 136 strips of 16
#define PADT2 152        // T strip row stride (bf16), 9 cbs = 144 + pad

typedef __attribute__((ext_vector_type(8))) short short8;
typedef __attribute__((ext_vector_type(4))) float f32x4;
typedef __attribute__((ext_vector_type(4))) int i32x4;
typedef unsigned short ushort_t;

static __device__ __forceinline__ ushort_t f2bf(float x) {
  unsigned u = __float_as_uint(x);
  return (ushort_t)((u + 0x7FFFu + ((u >> 16) & 1u)) >> 16);
}
static __device__ __forceinline__ float bf2f(ushort_t h) {
  return __uint_as_float(((unsigned)h) << 16);
}
static __device__ __forceinline__ unsigned cvt_pk_bf16(float lo, float hi) {
  unsigned r;
  asm("v_cvt_pk_bf16_f32 %0, %1, %2" : "=v"(r) : "v"(lo), "v"(hi));
  return r;
}

// Fragment-order layouts: one wave-load (64 lanes x 16B) = one MFMA operand.
static __device__ __forceinline__ size_t kf_off(int bn, int j, int d) {   // Kf & Qf
  return ((size_t)((bn*128 + (j>>4))*2 + (d>>5)))*512 + (((d&31)>>3)*16 + (j&15))*8 + (d&7);
}
static __device__ __forceinline__ size_t relf_off(int n, int g, int d) {  // RELf
  return ((size_t)((n*136 + (g>>4))*2 + (d>>5)))*512 + (((d&31)>>3)*16 + (g&15))*8 + (d&7);
}

// ---------------------------------------------------------------------------
// Kernel 1: QKV projection, bf16 MFMA, f32 inputs.  Q (pre-scaled) and K are
// scattered into FRAGMENT layout (Qf/Kf); V into row layout for vt_pack.
// ---------------------------------------------------------------------------
__global__ __launch_bounds__(256)
void qkv_mfma(const float* __restrict__ A, const float* __restrict__ B,
              ushort_t* __restrict__ Qf, ushort_t* __restrict__ Kf,
              ushort_t* __restrict__ Vo) {
  __shared__ __align__(16) ushort_t As[128*64];
  __shared__ __align__(16) ushort_t Bs[128*64];
  const int bx = blockIdx.x;        // 18 N-tiles
  const int by = blockIdx.y;        // 32 M-tiles
  const int rbase = by*128, cbase = bx*128;
  const int tid = threadIdx.x;
  const int wv = tid>>6, lane = tid&63, lrow = lane>>4, lcol = lane&15;
  const int wr = wv>>1, wc = wv&1;
  const int sr = tid>>3, sc = tid&7;

  f32x4 acc[4][4];
  #pragma unroll
  for (int m = 0; m < 4; ++m)
    #pragma unroll
    for (int nn = 0; nn < 4; ++nn)
      acc[m][nn] = (f32x4){0.f,0.f,0.f,0.f};

  for (int kk = 0; kk < DM; kk += 64) {
    __syncthreads();
    #pragma unroll
    for (int q = 0; q < 4; ++q) {
      const int row = sr + 32*q;
      const float4 a0 = *(const float4*)&A[(size_t)(rbase+row)*DM + kk + sc*8];
      const float4 a1 = *(const float4*)&A[(size_t)(rbase+row)*DM + kk + sc*8 + 4];
      i32x4 va = { (int)cvt_pk_bf16(a0.x,a0.y), (int)cvt_pk_bf16(a0.z,a0.w),
                   (int)cvt_pk_bf16(a1.x,a1.y), (int)cvt_pk_bf16(a1.z,a1.w) };
      *(short8*)((char*)As + row*128 + ((sc*16) ^ ((row&7)<<4))) = __builtin_bit_cast(short8, va);
      const float4 b0 = *(const float4*)&B[(size_t)(cbase+row)*DM + kk + sc*8];
      const float4 b1 = *(const float4*)&B[(size_t)(cbase+row)*DM + kk + sc*8 + 4];
      i32x4 vb = { (int)cvt_pk_bf16(b0.x,b0.y), (int)cvt_pk_bf16(b0.z,b0.w),
                   (int)cvt_pk_bf16(b1.x,b1.y), (int)cvt_pk_bf16(b1.z,b1.w) };
      *(short8*)((char*)Bs + row*128 + ((sc*16) ^ ((row&7)<<4))) = __builtin_bit_cast(short8, vb);
    }
    __syncthreads();
    short8 af[4][2], bfr[4][2];
    #pragma unroll
    for (int m = 0; m < 4; ++m) {
      const int row = wr*64 + m*16 + lcol;
      af[m][0] = *(const short8*)((const char*)As + row*128 + (((     lrow*16)) ^ ((row&7)<<4)));
      af[m][1] = *(const short8*)((const char*)As + row*128 + (((64 + lrow*16)) ^ ((row&7)<<4)));
    }
    #pragma unroll
    for (int nn = 0; nn < 4; ++nn) {
      const int row = wc*64 + nn*16 + lcol;
      bfr[nn][0] = *(const short8*)((const char*)Bs + row*128 + (((     lrow*16)) ^ ((row&7)<<4)));
      bfr[nn][1] = *(const short8*)((const char*)Bs + row*128 + (((64 + lrow*16)) ^ ((row&7)<<4)));
    }
    #pragma unroll
    for (int m = 0; m < 4; ++m)
      #pragma unroll
      for (int nn = 0; nn < 4; ++nn) {
        acc[m][nn] = __builtin_amdgcn_mfma_f32_16x16x32_bf16(af[m][0], bfr[nn][0], acc[m][nn], 0, 0, 0);
        acc[m][nn] = __builtin_amdgcn_mfma_f32_16x16x32_bf16(af[m][1], bfr[nn][1], acc[m][nn], 0, 0, 0);
      }
  }
  const int part = cbase / DM;      // uniform per block
  const float sc2 = (part == 0) ? SCALE : 1.0f;
  #pragma unroll
  for (int nn = 0; nn < 4; ++nn) {
    const int h  = cbase - part*DM + wc*64 + nn*16;
    const int nh = h >> 6;
    const int d  = (h & 63) + lcol;
    #pragma unroll
    for (int m = 0; m < 4; ++m)
      #pragma unroll
      for (int reg = 0; reg < 4; ++reg) {
        const int r = rbase + wr*64 + m*16 + lrow*4 + reg;
        const int i = r >> 1, b = r & 1;
        const int bn = b*NH + nh;
        const ushort_t val = f2bf(acc[m][nn][reg] * sc2);
        if (part == 0)      Qf[kf_off(bn, i, d)] = val;
        else if (part == 1) Kf[kf_off(bn, i, d)] = val;
        else                Vo[((size_t)bn*QLEN + i)*DH + d] = val;
      }
  }
}

// ---------------------------------------------------------------------------
// Kernel 2: V bf16 [bn][j][d] -> Vtf fragment layout (LDS transpose)
// ---------------------------------------------------------------------------
__global__ __launch_bounds__(256)
void vt_pack(const ushort_t* __restrict__ V, ushort_t* __restrict__ Vtf) {
  __shared__ ushort_t Ls[64][72];
  const int jt = blockIdx.x, bn = blockIdx.y;
  const int tid = threadIdx.x;
  const size_t base = (size_t)bn * (QLEN*DH);
  #pragma unroll
  for (int q = 0; q < 2; ++q) {
    const int row = (tid>>3) + 32*q;
    const int c8  = (tid&7)*8;
    *(short8*)&Ls[row][c8] = *(const short8*)&V[base + (size_t)(jt*64+row)*DH + c8];
  }
  __syncthreads();
  #pragma unroll
  for (int h = 0; h < 2; ++h) {
    const int unit = tid + h*256;           // [0,512): (dstrip, jblk, lane)
    const int ds = unit >> 7;               // 0..3
    const int jb = (unit >> 6) & 1;         // 0..1
    const int l  = unit & 63;
    const int dl = ds*16 + (l & 15);
    const int jl = jb*32 + (l >> 4)*8;
    short8 o;
    #pragma unroll
    for (int e = 0; e < 8; ++e) o[e] = (short)Ls[jl + e][dl];
    *(short8*)&Vtf[((size_t)((bn*4 + ds)*64 + jt*2 + jb))*512 + l*8] = o;
  }
}

// ---------------------------------------------------------------------------
// Kernel 3: r_emb -> RELf fragment layout (zero pad); rbias*SCALE -> rbp
// ---------------------------------------------------------------------------
__global__ __launch_bounds__(256)
void rel_pack(const float* __restrict__ remb, const float* __restrict__ rbias,
              ushort_t* __restrict__ RELf, float* __restrict__ rbp) {
  const int n = blockIdx.y;
  const int g = blockIdx.x*4 + (threadIdx.x >> 6);
  const int d = threadIdx.x & 63;
  const bool ok = g < QLEN;
  const float v = ok ? remb[((size_t)g*NH + n)*DH + d] : 0.f;
  RELf[relf_off(n, g, d)] = f2bf(v);
  if (d == 0) rbp[n*RELROWS + g] = (ok ? rbias[g*NH + n] : 0.f) * SCALE;
}

// ---------------------------------------------------------------------------
// Kernel 4: KB[b,n,j] = dot(r_w_bias[n], K[b,n,j,:]) * SCALE  (gather from Kf)
// ---------------------------------------------------------------------------
__global__ __launch_bounds__(256)
void kbias_kernel(const ushort_t* __restrict__ Kf, const float* __restrict__ rwb,
                  float* __restrict__ KB) {
  const int wv = threadIdx.x >> 6, lane = threadIdx.x & 63;
  const int row = blockIdx.x*4 + wv;             // (b*NH+n)*QLEN + j
  const int bn = row >> 11, j = row & (QLEN-1);
  const int n = bn % NH;
  float v = bf2f(Kf[kf_off(bn, j, lane)]) * rwb[n*DH + lane];
  #pragma unroll
  for (int o = 32; o > 0; o >>= 1) v += __shfl_xor(v, o, 64);
  if (lane == 0) KB[row] = v * SCALE;
}

// ---------------------------------------------------------------------------
// Kernel 5: MFMA flash attention — EXACT R8 body (proven correct), with the
// single change __launch_bounds__(512, 6) -> (512, 4): VGPR cap 84 -> 128 so
// the 32-reg S-tile stays in registers (R8 spilled: 162MB FETCH + 319MB WRITE
// of scratch traffic, VGPR_Count=40).  One variable changed for isolation.
// ---------------------------------------------------------------------------
#define TW_BYTES (16*PADT2*2)          // 4864 per wave
#define SMEM_A   (8*TW_BYTES)          // 38912; merge overlay 128*68*4+1024 fits

__global__ __launch_bounds__(512, 4)
void attn_kernel(const ushort_t* __restrict__ Qf,
                 const ushort_t* __restrict__ Kf,
                 const ushort_t* __restrict__ Vtf,
                 const ushort_t* __restrict__ RELf,
                 const float* __restrict__ rbp,
                 const float* __restrict__ KB,
                 ushort_t* __restrict__ AV) {
  __shared__ __align__(16) char smem[SMEM_A];
  const int f    = blockIdx.x;
  const int wu   = (f & 7)*384 + (f >> 3);     // XCD k -> bn in [3k, 3k+3)
  const int bn   = wu >> 7;
  const int it16 = 127 - (wu & 127);           // heavy tiles first within bn
  const int n    = bn % NH;
  const int tid  = threadIdx.x;
  const int wv = tid >> 6, lane = tid & 63;
  const int lrow = lane >> 4, lcol = lane & 15;
  const int ib = it16*16;
  ushort_t* Tw = (ushort_t*)(smem + wv*TW_BYTES);

  // Q A-fragment: one coalesced pair of wave-loads
  const size_t qo = ((size_t)((bn*128 + it16)*2))*512 + lane*8;
  const short8 qf0 = *(const short8*)&Qf[qo];
  const short8 qf1 = *(const short8*)&Qf[qo + 512];

  f32x4 accO[4];                 // O^T: accO[cb][reg] = O[q=lcol][d=cb*16+lrow*4+reg]
  float mreg = -1.0e30f, lreg = 0.f;
  #pragma unroll
  for (int r = 0; r < 4; ++r) accO[r] = (f32x4){0.f,0.f,0.f,0.f};

  const int NT = (it16 >> 3) + 1;
  for (int t = wv; t < NT; t += 8) {
    const int j0 = t*128;
    const int gbase = 2032 + j0 - ib;          // = 0 (mod 16), in [0, 2032]
    const int gs = gbase >> 4;
    // ---- T strip = Qs*REL^T + rbias (9 cbs, coalesced frag loads) ----
    #pragma unroll
    for (int cb = 0; cb < 9; ++cb) {
      const size_t ro = ((size_t)((n*136 + gs + cb)*2))*512 + lane*8;
      const short8 r0 = *(const short8*)&RELf[ro];
      const short8 r1 = *(const short8*)&RELf[ro + 512];
      f32x4 tt = (f32x4){0.f,0.f,0.f,0.f};
      tt = __builtin_amdgcn_mfma_f32_16x16x32_bf16(qf0, r0, tt, 0, 0, 0);
      tt = __builtin_amdgcn_mfma_f32_16x16x32_bf16(qf1, r1, tt, 0, 0, 0);
      const float rb = rbp[n*RELROWS + gbase + cb*16 + lcol];
      #pragma unroll
      for (int reg = 0; reg < 4; ++reg)       // T[q=lrow*4+reg][relcol=cb*16+lcol]
        Tw[(lrow*4 + reg)*PADT2 + cb*16 + lcol] = f2bf(tt[reg] + rb);
    }
    // ---- S^T = K * Qs^T (8 cbs = 128 keys, coalesced frag loads) ----
    f32x4 s[8];
    #pragma unroll
    for (int cb = 0; cb < 8; ++cb) {
      const size_t ko = ((size_t)((bn*128 + (j0>>4) + cb)*2))*512 + lane*8;
      const short8 k0 = *(const short8*)&Kf[ko];
      const short8 k1 = *(const short8*)&Kf[ko + 512];
      f32x4 a = (f32x4){0.f,0.f,0.f,0.f};
      a = __builtin_amdgcn_mfma_f32_16x16x32_bf16(k0, qf0, a, 0, 0, 0);
      a = __builtin_amdgcn_mfma_f32_16x16x32_bf16(k1, qf1, a, 0, 0, 0);
      s[cb] = a;                               // S^T[key=cb*16+lrow*4+reg][q=lcol]
    }
    // ---- + T(diag) + KB, causal mask ----
    #pragma unroll
    for (int cb = 0; cb < 8; ++cb) {
      const float4 kb4 = *(const float4*)&KB[bn*QLEN + j0 + cb*16 + lrow*4];
      const float kbr[4] = {kb4.x, kb4.y, kb4.z, kb4.w};
      #pragma unroll
      for (int reg = 0; reg < 4; ++reg) {
        const int kl = cb*16 + lrow*4 + reg;
        const int tc = 15 + kl - lcol;         // [0, 142]
        const float sv = s[cb][reg] + bf2f(Tw[lcol*PADT2 + tc]) + kbr[reg];
        s[cb][reg] = (j0 + kl > ib + lcol) ? -3.0e38f : sv;
      }
    }
    // ---- online softmax (per-q via xor 16/32 over 4 lrow lanes) ----
    float mx = s[0][0];
    #pragma unroll
    for (int cb = 0; cb < 8; ++cb)
      #pragma unroll
      for (int reg = 0; reg < 4; ++reg) mx = fmaxf(mx, s[cb][reg]);
    mx = fmaxf(mx, __shfl_xor(mx, 16, 64));
    mx = fmaxf(mx, __shfl_xor(mx, 32, 64));
    const float mn = fmaxf(mreg, mx);
    const float al = __expf(mreg - mn);
    mreg = mn;
    float ps = 0.f;
    unsigned pk[8][2];
    #pragma unroll
    for (int cb = 0; cb < 8; ++cb) {
      float p0 = __expf(s[cb][0] - mn), p1 = __expf(s[cb][1] - mn);
      float p2 = __expf(s[cb][2] - mn), p3 = __expf(s[cb][3] - mn);
      ps += (p0 + p1) + (p2 + p3);
      pk[cb][0] = cvt_pk_bf16(p0, p1);
      pk[cb][1] = cvt_pk_bf16(p2, p3);
    }
    ps += __shfl_xor(ps, 16, 64);
    ps += __shfl_xor(ps, 32, 64);
    lreg = lreg*al + ps;
    #pragma unroll
    for (int cb = 0; cb < 4; ++cb)            // O^T rescale: al is lane-local (q=lcol)
      #pragma unroll
      for (int reg = 0; reg < 4; ++reg) accO[cb][reg] *= al;
    // ---- P^T B-fragments via shfl; O^T += V^T * P^T ----
    const int srcA = ((lrow & 1) << 5) + lcol;
    const int srcB = srcA + 16;
    const bool hi2 = (lrow >> 1) != 0;
    #pragma unroll
    for (int ks = 0; ks < 4; ++ks) {
      const unsigned a0 = (unsigned)__shfl((int)pk[2*ks  ][0], srcA, 64);
      const unsigned b0 = (unsigned)__shfl((int)pk[2*ks+1][0], srcA, 64);
      const unsigned a1 = (unsigned)__shfl((int)pk[2*ks  ][1], srcA, 64);
      const unsigned b1 = (unsigned)__shfl((int)pk[2*ks+1][1], srcA, 64);
      const unsigned a2 = (unsigned)__shfl((int)pk[2*ks  ][0], srcB, 64);
      const unsigned b2 = (unsigned)__shfl((int)pk[2*ks+1][0], srcB, 64);
      const unsigned a3 = (unsigned)__shfl((int)pk[2*ks  ][1], srcB, 64);
      const unsigned b3 = (unsigned)__shfl((int)pk[2*ks+1][1], srcB, 64);
      i32x4 pw = { (int)(hi2 ? b0 : a0), (int)(hi2 ? b1 : a1),
                   (int)(hi2 ? b2 : a2), (int)(hi2 ? b3 : a3) };
      const short8 pb = __builtin_bit_cast(short8, pw);
      #pragma unroll
      for (int cb = 0; cb < 4; ++cb) {
        const short8 vf = *(const short8*)&Vtf[((size_t)((bn*4 + cb)*64 + t*4 + ks))*512 + lane*8];
        accO[cb] = __builtin_amdgcn_mfma_f32_16x16x32_bf16(vf, pb, accO[cb], 0, 0, 0);
      }
    }
  }
  // ---- cross-wave merge in LDS (handles O^T -> O transpose) ----
  __syncthreads();
  float* Macc = (float*)smem;                        // [128][68]: row = wv*16 + q
  float* Mm   = (float*)(smem + 128*68*4);           // [128]
  float* Ml   = Mm + 128;
  #pragma unroll
  for (int cb = 0; cb < 4; ++cb)
    #pragma unroll
    for (int reg = 0; reg < 4; ++reg)
      Macc[(wv*16 + lcol)*68 + cb*16 + lrow*4 + reg] = accO[cb][reg];
  if (lrow == 0) { Mm[wv*16 + lcol] = mreg; Ml[wv*16 + lcol] = lreg; }
  __syncthreads();
  #pragma unroll
  for (int h = 0; h < 2; ++h) {
    const int o = tid + h*512;
    const int row = o >> 6, col = o & 63;            // q-row 0..15, d 0..63
    float M = Mm[row];
    #pragma unroll
    for (int w2 = 1; w2 < 8; ++w2) M = fmaxf(M, Mm[w2*16 + row]);
    float L = 0.f, V = 0.f;
    #pragma unroll
    for (int w2 = 0; w2 < 8; ++w2) {
      const float e = __expf(Mm[w2*16 + row] - M);
      L += Ml[w2*16 + row] * e;
      V += Macc[(w2*16 + row)*68 + col] * e;
    }
    AV[((size_t)bn*QLEN + ib + row)*DH + col] = f2bf(V / L);
  }
}

// ---------------------------------------------------------------------------
// Kernel 6: O-projection, bf16 MFMA; B = o_w f32 (pack fused into staging).
// ---------------------------------------------------------------------------
__global__ __launch_bounds__(256)
void oproj_mfma(const ushort_t* __restrict__ AVp, const float* __restrict__ B,
                float* __restrict__ AO) {
  __shared__ __align__(16) ushort_t As[128*64];
  __shared__ __align__(16) ushort_t Bs[128*64];
  const int bx = blockIdx.x;        // 6 N-tiles
  const int by = blockIdx.y;        // 32 M-tiles
  const int rbase = by*128, cbase = bx*128;
  const int tid = threadIdx.x;
  const int wv = tid>>6, lane = tid&63, lrow = lane>>4, lcol = lane&15;
  const int wr = wv>>1, wc = wv&1;
  const int sr = tid>>3, sc = tid&7;

  f32x4 acc[4][4];
  #pragma unroll
  for (int m = 0; m < 4; ++m)
    #pragma unroll
    for (int nn = 0; nn < 4; ++nn)
      acc[m][nn] = (f32x4){0.f,0.f,0.f,0.f};

  for (int kk = 0; kk < DM; kk += 64) {
    const int nh = kk >> 6;         // head index
    __syncthreads();
    #pragma unroll
    for (int q = 0; q < 4; ++q) {
      const int row = sr + 32*q;
      const int r = rbase + row, i = r >> 1, b = r & 1;
      const short8 va = *(const short8*)&AVp[((size_t)(b*NH + nh)*QLEN + i)*DH + sc*8];
      *(short8*)((char*)As + row*128 + ((sc*16) ^ ((row&7)<<4))) = va;
      const float4 b0 = *(const float4*)&B[(size_t)(cbase+row)*DM + kk + sc*8];
      const float4 b1 = *(const float4*)&B[(size_t)(cbase+row)*DM + kk + sc*8 + 4];
      i32x4 vb = { (int)cvt_pk_bf16(b0.x,b0.y), (int)cvt_pk_bf16(b0.z,b0.w),
                   (int)cvt_pk_bf16(b1.x,b1.y), (int)cvt_pk_bf16(b1.z,b1.w) };
      *(short8*)((char*)Bs + row*128 + ((sc*16) ^ ((row&7)<<4))) = __builtin_bit_cast(short8, vb);
    }
    __syncthreads();
    short8 af[4][2], bfr[4][2];
    #pragma unroll
    for (int m = 0; m < 4; ++m) {
      const int row = wr*64 + m*16 + lcol;
      af[m][0] = *(const short8*)((const char*)As + row*128 + (((     lrow*16)) ^ ((row&7)<<4)));
      af[m][1] = *(const short8*)((const char*)As + row*128 + (((64 + lrow*16)) ^ ((row&7)<<4)));
    }
    #pragma unroll
    for (int nn = 0; nn < 4; ++nn) {
      const int row = wc*64 + nn*16 + lcol;
      bfr[nn][0] = *(const short8*)((const char*)Bs + row*128 + (((     lrow*16)) ^ ((row&7)<<4)));
      bfr[nn][1] = *(const short8*)((const char*)Bs + row*128 + (((64 + lrow*16)) ^ ((row&7)<<4)));
    }
    #pragma unroll
    for (int m = 0; m < 4; ++m)
      #pragma unroll
      for (int nn = 0; nn < 4; ++nn) {
        acc[m][nn] = __builtin_amdgcn_mfma_f32_16x16x32_bf16(af[m][0], bfr[nn][0], acc[m][nn], 0, 0, 0);
        acc[m][nn] = __builtin_amdgcn_mfma_f32_16x16x32_bf16(af[m][1], bfr[nn][1], acc[m][nn], 0, 0, 0);
      }
  }
  #pragma unroll
  for (int nn = 0; nn < 4; ++nn) {
    const int mcol = cbase + wc*64 + nn*16 + lcol;
    #pragma unroll
    for (int mi = 0; mi < 4; ++mi)
      #pragma unroll
      for (int reg = 0; reg < 4; ++reg) {
        const int r = rbase + wr*64 + mi*16 + lrow*4 + reg;
        AO[(size_t)r*DM + mcol] = acc[mi][nn][reg];
      }
  }
}

// ---------------------------------------------------------------------------
// Kernel 7: residual + LayerNorm.
// ---------------------------------------------------------------------------
__global__ __launch_bounds__(256)
void ln_kernel(const float* __restrict__ AO, const float* __restrict__ W,
               const float* __restrict__ gamma, const float* __restrict__ beta,
               float* __restrict__ out) {
  const int r = blockIdx.x;
  const int tid = threadIdx.x;
  const int wv = tid >> 6, lane = tid & 63;
  float x[3];
  #pragma unroll
  for (int q = 0; q < 3; ++q) {
    const int mcol = tid + q*256;
    x[q] = AO[(size_t)r*DM + mcol] + W[(size_t)r*DM + mcol];
  }
  float s1 = x[0] + x[1] + x[2];
  float s2 = x[0]*x[0] + x[1]*x[1] + x[2]*x[2];
  #pragma unroll
  for (int o = 32; o > 0; o >>= 1) { s1 += __shfl_xor(s1, o, 64); s2 += __shfl_xor(s2, o, 64); }
  __shared__ float a1[4], a2[4];
  if (lane == 0) { a1[wv] = s1; a2[wv] = s2; }
  __syncthreads();
  s1 = a1[0] + a1[1] + a1[2] + a1[3];
  s2 = a2[0] + a2[1] + a2[2] + a2[3];
  const float mu  = s1 * (1.0f/DM);
  const float var = s2 * (1.0f/DM) - mu*mu;
  const float rs  = rsqrtf(var + 1e-5f);
  #pragma unroll
  for (int q = 0; q < 3; ++q) {
    const int mcol = tid + q*256;
    out[(size_t)r*DM + mcol] = (x[q] - mu)*rs*gamma[mcol] + beta[mcol];
  }
}

// ---------------------------------------------------------------------------
extern "C" void kernel_launch(void* const* d_in, const int* in_sizes, int n_in,
                              void* d_out, int out_size, void* d_ws, size_t ws_size,
                              hipStream_t stream) {
  const float* w      = (const float*)d_in[0];
  const float* r_emb  = (const float*)d_in[1];
  const float* r_wb   = (const float*)d_in[2];
  const float* r_bias = (const float*)d_in[3];
  const float* qkv_w  = (const float*)d_in[4];
  const float* o_w    = (const float*)d_in[5];
  const float* ln_g   = (const float*)d_in[6];
  const float* ln_b   = (const float*)d_in[7];
  float* out = (float*)d_out;

  const size_t QS = (size_t)BSZ*NH*QLEN*DH;       // 3,145,728 elems
  ushort_t* u     = (ushort_t*)d_ws;
  ushort_t* Vb16  = u;                            // QS (dead after vt_pack)
  ushort_t* AVb16 = Vb16;                         // overlay: written by attn
  ushort_t* Qfb   = u + QS;
  ushort_t* Kfb   = Qfb + QS;
  ushort_t* Vtf   = Kfb + QS;
  ushort_t* RELf  = Vtf + QS;                     // NH*RELROWS*DH
  float* rbp = (float*)(RELf + (size_t)NH*RELROWS*DH);
  float* KBb = rbp + NH*RELROWS;                  // 49152 f32
  float* AO  = (float*)Qfb;                       // overlays Qf+Kf (dead by oproj)

  qkv_mfma<<<dim3(HID/128, (QLEN*BSZ)/128), dim3(256), 0, stream>>>(w, qkv_w, Qfb, Kfb, Vb16);
  vt_pack<<<dim3(QLEN/64, BSZ*NH), dim3(256), 0, stream>>>(Vb16, Vtf);
  rel_pack<<<dim3(RELROWS/4, NH), dim3(256), 0, stream>>>(r_emb, r_bias, RELf, rbp);
  kbias_kernel<<<dim3(BSZ*NH*QLEN/4), dim3(256), 0, stream>>>(Kfb, r_wb, KBb);
  attn_kernel<<<dim3(3072), dim3(512), 0, stream>>>(Qfb, Kfb, Vtf, RELf, rbp, KBb, AVb16);
  oproj_mfma<<<dim3(DM/128, (QLEN*BSZ)/128), dim3(256), 0, stream>>>(AVb16, o_w, AO);
  ln_kernel<<<dim3(QLEN*BSZ), dim3(256), 0, stream>>>(AO, w, ln_g, ln_b, out);
}

// Round 11
// 199.824 us; speedup vs baseline: 1.7318x; 1.0659x over previous
//
#include <hip/hip_runtime.h>

#define QLEN 2048
#define BSZ  2
#define NH   12
#define DH   64
#define DM   768
#define HID  2304
#define SCALE 0.125f
#define RELROWS 2176     // 2048 + 128 zero pad; 136 strips of 16
#define PADT2 152        // T strip row stride (bf16), 9 cbs = 144 + pad

typedef __attribute__((ext_vector_type(8))) short short8;
typedef __attribute__((ext_vector_type(4))) float f32x4;
typedef __attribute__((ext_vector_type(4))) int i32x4;
typedef unsigned short ushort_t;

static __device__ __forceinline__ ushort_t f2bf(float x) {
  unsigned u = __float_as_uint(x);
  return (ushort_t)((u + 0x7FFFu + ((u >> 16) & 1u)) >> 16);
}
static __device__ __forceinline__ float bf2f(ushort_t h) {
  return __uint_as_float(((unsigned)h) << 16);
}
static __device__ __forceinline__ unsigned cvt_pk_bf16(float lo, float hi) {
  unsigned r;
  asm("v_cvt_pk_bf16_f32 %0, %1, %2" : "=v"(r) : "v"(lo), "v"(hi));
  return r;
}

// Fragment-order layouts: one wave-load (64 lanes x 16B) = one MFMA operand.
static __device__ __forceinline__ size_t kf_off(int bn, int j, int d) {   // Kf & Qf
  return ((size_t)((bn*128 + (j>>4))*2 + (d>>5)))*512 + (((d&31)>>3)*16 + (j&15))*8 + (d&7);
}
static __device__ __forceinline__ size_t relf_off(int n, int g, int d) {  // RELf
  return ((size_t)((n*136 + (g>>4))*2 + (d>>5)))*512 + (((d&31)>>3)*16 + (g&15))*8 + (d&7);
}

// ---------------------------------------------------------------------------
// Kernel 1: QKV projection, bf16 MFMA, f32 inputs.  Q (pre-scaled) and K are
// scattered into FRAGMENT layout (Qf/Kf); V into row layout for vt_pack.
// ---------------------------------------------------------------------------
__global__ __launch_bounds__(256)
void qkv_mfma(const float* __restrict__ A, const float* __restrict__ B,
              ushort_t* __restrict__ Qf, ushort_t* __restrict__ Kf,
              ushort_t* __restrict__ Vo) {
  __shared__ __align__(16) ushort_t As[128*64];
  __shared__ __align__(16) ushort_t Bs[128*64];
  const int bx = blockIdx.x;        // 18 N-tiles
  const int by = blockIdx.y;        // 32 M-tiles
  const int rbase = by*128, cbase = bx*128;
  const int tid = threadIdx.x;
  const int wv = tid>>6, lane = tid&63, lrow = lane>>4, lcol = lane&15;
  const int wr = wv>>1, wc = wv&1;
  const int sr = tid>>3, sc = tid&7;

  f32x4 acc[4][4];
  #pragma unroll
  for (int m = 0; m < 4; ++m)
    #pragma unroll
    for (int nn = 0; nn < 4; ++nn)
      acc[m][nn] = (f32x4){0.f,0.f,0.f,0.f};

  for (int kk = 0; kk < DM; kk += 64) {
    __syncthreads();
    #pragma unroll
    for (int q = 0; q < 4; ++q) {
      const int row = sr + 32*q;
      const float4 a0 = *(const float4*)&A[(size_t)(rbase+row)*DM + kk + sc*8];
      const float4 a1 = *(const float4*)&A[(size_t)(rbase+row)*DM + kk + sc*8 + 4];
      i32x4 va = { (int)cvt_pk_bf16(a0.x,a0.y), (int)cvt_pk_bf16(a0.z,a0.w),
                   (int)cvt_pk_bf16(a1.x,a1.y), (int)cvt_pk_bf16(a1.z,a1.w) };
      *(short8*)((char*)As + row*128 + ((sc*16) ^ ((row&7)<<4))) = __builtin_bit_cast(short8, va);
      const float4 b0 = *(const float4*)&B[(size_t)(cbase+row)*DM + kk + sc*8];
      const float4 b1 = *(const float4*)&B[(size_t)(cbase+row)*DM + kk + sc*8 + 4];
      i32x4 vb = { (int)cvt_pk_bf16(b0.x,b0.y), (int)cvt_pk_bf16(b0.z,b0.w),
                   (int)cvt_pk_bf16(b1.x,b1.y), (int)cvt_pk_bf16(b1.z,b1.w) };
      *(short8*)((char*)Bs + row*128 + ((sc*16) ^ ((row&7)<<4))) = __builtin_bit_cast(short8, vb);
    }
    __syncthreads();
    short8 af[4][2], bfr[4][2];
    #pragma unroll
    for (int m = 0; m < 4; ++m) {
      const int row = wr*64 + m*16 + lcol;
      af[m][0] = *(const short8*)((const char*)As + row*128 + (((     lrow*16)) ^ ((row&7)<<4)));
      af[m][1] = *(const short8*)((const char*)As + row*128 + (((64 + lrow*16)) ^ ((row&7)<<4)));
    }
    #pragma unroll
    for (int nn = 0; nn < 4; ++nn) {
      const int row = wc*64 + nn*16 + lcol;
      bfr[nn][0] = *(const short8*)((const char*)Bs + row*128 + (((     lrow*16)) ^ ((row&7)<<4)));
      bfr[nn][1] = *(const short8*)((const char*)Bs + row*128 + (((64 + lrow*16)) ^ ((row&7)<<4)));
    }
    #pragma unroll
    for (int m = 0; m < 4; ++m)
      #pragma unroll
      for (int nn = 0; nn < 4; ++nn) {
        acc[m][nn] = __builtin_amdgcn_mfma_f32_16x16x32_bf16(af[m][0], bfr[nn][0], acc[m][nn], 0, 0, 0);
        acc[m][nn] = __builtin_amdgcn_mfma_f32_16x16x32_bf16(af[m][1], bfr[nn][1], acc[m][nn], 0, 0, 0);
      }
  }
  const int part = cbase / DM;      // uniform per block
  const float sc2 = (part == 0) ? SCALE : 1.0f;
  #pragma unroll
  for (int nn = 0; nn < 4; ++nn) {
    const int h  = cbase - part*DM + wc*64 + nn*16;
    const int nh = h >> 6;
    const int d  = (h & 63) + lcol;
    #pragma unroll
    for (int m = 0; m < 4; ++m)
      #pragma unroll
      for (int reg = 0; reg < 4; ++reg) {
        const int r = rbase + wr*64 + m*16 + lrow*4 + reg;
        const int i = r >> 1, b = r & 1;
        const int bn = b*NH + nh;
        const ushort_t val = f2bf(acc[m][nn][reg] * sc2);
        if (part == 0)      Qf[kf_off(bn, i, d)] = val;
        else if (part == 1) Kf[kf_off(bn, i, d)] = val;
        else                Vo[((size_t)bn*QLEN + i)*DH + d] = val;
      }
  }
}

// ---------------------------------------------------------------------------
// Kernel 2: V bf16 [bn][j][d] -> Vtf fragment layout (LDS transpose)
// ---------------------------------------------------------------------------
__global__ __launch_bounds__(256)
void vt_pack(const ushort_t* __restrict__ V, ushort_t* __restrict__ Vtf) {
  __shared__ ushort_t Ls[64][72];
  const int jt = blockIdx.x, bn = blockIdx.y;
  const int tid = threadIdx.x;
  const size_t base = (size_t)bn * (QLEN*DH);
  #pragma unroll
  for (int q = 0; q < 2; ++q) {
    const int row = (tid>>3) + 32*q;
    const int c8  = (tid&7)*8;
    *(short8*)&Ls[row][c8] = *(const short8*)&V[base + (size_t)(jt*64+row)*DH + c8];
  }
  __syncthreads();
  #pragma unroll
  for (int h = 0; h < 2; ++h) {
    const int unit = tid + h*256;           // [0,512): (dstrip, jblk, lane)
    const int ds = unit >> 7;               // 0..3
    const int jb = (unit >> 6) & 1;         // 0..1
    const int l  = unit & 63;
    const int dl = ds*16 + (l & 15);
    const int jl = jb*32 + (l >> 4)*8;
    short8 o;
    #pragma unroll
    for (int e = 0; e < 8; ++e) o[e] = (short)Ls[jl + e][dl];
    *(short8*)&Vtf[((size_t)((bn*4 + ds)*64 + jt*2 + jb))*512 + l*8] = o;
  }
}

// ---------------------------------------------------------------------------
// Kernel 3: r_emb -> RELf fragment layout (zero pad); rbias*SCALE -> rbp
// ---------------------------------------------------------------------------
__global__ __launch_bounds__(256)
void rel_pack(const float* __restrict__ remb, const float* __restrict__ rbias,
              ushort_t* __restrict__ RELf, float* __restrict__ rbp) {
  const int n = blockIdx.y;
  const int g = blockIdx.x*4 + (threadIdx.x >> 6);
  const int d = threadIdx.x & 63;
  const bool ok = g < QLEN;
  const float v = ok ? remb[((size_t)g*NH + n)*DH + d] : 0.f;
  RELf[relf_off(n, g, d)] = f2bf(v);
  if (d == 0) rbp[n*RELROWS + g] = (ok ? rbias[g*NH + n] : 0.f) * SCALE;
}

// ---------------------------------------------------------------------------
// Kernel 4: KB[b,n,j] = dot(r_w_bias[n], K[b,n,j,:]) * SCALE  (gather from Kf)
// ---------------------------------------------------------------------------
__global__ __launch_bounds__(256)
void kbias_kernel(const ushort_t* __restrict__ Kf, const float* __restrict__ rwb,
                  float* __restrict__ KB) {
  const int wv = threadIdx.x >> 6, lane = threadIdx.x & 63;
  const int row = blockIdx.x*4 + wv;             // (b*NH+n)*QLEN + j
  const int bn = row >> 11, j = row & (QLEN-1);
  const int n = bn % NH;
  float v = bf2f(Kf[kf_off(bn, j, lane)]) * rwb[n*DH + lane];
  #pragma unroll
  for (int o = 32; o > 0; o >>= 1) v += __shfl_xor(v, o, 64);
  if (lane == 0) KB[row] = v * SCALE;
}

// ---------------------------------------------------------------------------
// Kernel 5: MFMA flash attention — R10 math byte-identical; ONLY change is
// explicit BATCHED operand loads (R10: VGPR_Count=64 forced serial load->use
// chains, ~50 waits/iter at ~700cy = the 120us; all pipes <31% busy).
// Batches: REL 5+4 cbs, K 4+4 cbs, Vtf 2+2 ks; rbp 9 scalars up-front.
// Peak live ~105 VGPR < 128 cap of (512,4).
// ---------------------------------------------------------------------------
#define TW_BYTES (16*PADT2*2)          // 4864 per wave
#define SMEM_A   (8*TW_BYTES)          // 38912; merge overlay 128*68*4+1024 fits

__global__ __launch_bounds__(512, 4)
void attn_kernel(const ushort_t* __restrict__ Qf,
                 const ushort_t* __restrict__ Kf,
                 const ushort_t* __restrict__ Vtf,
                 const ushort_t* __restrict__ RELf,
                 const float* __restrict__ rbp,
                 const float* __restrict__ KB,
                 ushort_t* __restrict__ AV) {
  __shared__ __align__(16) char smem[SMEM_A];
  const int f    = blockIdx.x;
  const int wu   = (f & 7)*384 + (f >> 3);     // XCD k -> bn in [3k, 3k+3)
  const int bn   = wu >> 7;
  const int it16 = 127 - (wu & 127);           // heavy tiles first within bn
  const int n    = bn % NH;
  const int tid  = threadIdx.x;
  const int wv = tid >> 6, lane = tid & 63;
  const int lrow = lane >> 4, lcol = lane & 15;
  const int ib = it16*16;
  ushort_t* Tw = (ushort_t*)(smem + wv*TW_BYTES);

  // Q A-fragment: one coalesced pair of wave-loads
  const size_t qo = ((size_t)((bn*128 + it16)*2))*512 + lane*8;
  const short8 qf0 = *(const short8*)&Qf[qo];
  const short8 qf1 = *(const short8*)&Qf[qo + 512];

  f32x4 accO[4];                 // O^T: accO[cb][reg] = O[q=lcol][d=cb*16+lrow*4+reg]
  float mreg = -1.0e30f, lreg = 0.f;
  #pragma unroll
  for (int r = 0; r < 4; ++r) accO[r] = (f32x4){0.f,0.f,0.f,0.f};

  const int NT = (it16 >> 3) + 1;
  for (int t = wv; t < NT; t += 8) {
    const int j0 = t*128;
    const int gbase = 2032 + j0 - ib;          // = 0 (mod 16), in [0, 2032]
    const int gs = gbase >> 4;
    // ---- rbias scalars batched ----
    float rbv[9];
    #pragma unroll
    for (int cb = 0; cb < 9; ++cb)
      rbv[cb] = rbp[n*RELROWS + gbase + cb*16 + lcol];
    // ---- T strip = Qs*REL^T + rbias: REL loads batched 5 + 4 ----
    {
      short8 rl[5][2];
      #pragma unroll
      for (int cb = 0; cb < 5; ++cb) {
        const size_t ro = ((size_t)((n*136 + gs + cb)*2))*512 + lane*8;
        rl[cb][0] = *(const short8*)&RELf[ro];
        rl[cb][1] = *(const short8*)&RELf[ro + 512];
      }
      #pragma unroll
      for (int cb = 0; cb < 5; ++cb) {
        f32x4 tt = (f32x4){0.f,0.f,0.f,0.f};
        tt = __builtin_amdgcn_mfma_f32_16x16x32_bf16(qf0, rl[cb][0], tt, 0, 0, 0);
        tt = __builtin_amdgcn_mfma_f32_16x16x32_bf16(qf1, rl[cb][1], tt, 0, 0, 0);
        #pragma unroll
        for (int reg = 0; reg < 4; ++reg)
          Tw[(lrow*4 + reg)*PADT2 + cb*16 + lcol] = f2bf(tt[reg] + rbv[cb]);
      }
    }
    {
      short8 rl[4][2];
      #pragma unroll
      for (int cb = 0; cb < 4; ++cb) {
        const size_t ro = ((size_t)((n*136 + gs + 5 + cb)*2))*512 + lane*8;
        rl[cb][0] = *(const short8*)&RELf[ro];
        rl[cb][1] = *(const short8*)&RELf[ro + 512];
      }
      #pragma unroll
      for (int cb = 0; cb < 4; ++cb) {
        f32x4 tt = (f32x4){0.f,0.f,0.f,0.f};
        tt = __builtin_amdgcn_mfma_f32_16x16x32_bf16(qf0, rl[cb][0], tt, 0, 0, 0);
        tt = __builtin_amdgcn_mfma_f32_16x16x32_bf16(qf1, rl[cb][1], tt, 0, 0, 0);
        #pragma unroll
        for (int reg = 0; reg < 4; ++reg)
          Tw[(lrow*4 + reg)*PADT2 + (5+cb)*16 + lcol] = f2bf(tt[reg] + rbv[5+cb]);
      }
    }
    // ---- S^T = K * Qs^T: K loads batched 4 + 4 ----
    f32x4 s[8];
    #pragma unroll
    for (int half = 0; half < 2; ++half) {
      short8 kl[4][2];
      #pragma unroll
      for (int cb = 0; cb < 4; ++cb) {
        const size_t ko = ((size_t)((bn*128 + (j0>>4) + half*4 + cb)*2))*512 + lane*8;
        kl[cb][0] = *(const short8*)&Kf[ko];
        kl[cb][1] = *(const short8*)&Kf[ko + 512];
      }
      #pragma unroll
      for (int cb = 0; cb < 4; ++cb) {
        f32x4 a = (f32x4){0.f,0.f,0.f,0.f};
        a = __builtin_amdgcn_mfma_f32_16x16x32_bf16(kl[cb][0], qf0, a, 0, 0, 0);
        a = __builtin_amdgcn_mfma_f32_16x16x32_bf16(kl[cb][1], qf1, a, 0, 0, 0);
        s[half*4 + cb] = a;                    // S^T[key=..][q=lcol]
      }
    }
    // ---- + T(diag) + KB, causal mask ----
    #pragma unroll
    for (int cb = 0; cb < 8; ++cb) {
      const float4 kb4 = *(const float4*)&KB[bn*QLEN + j0 + cb*16 + lrow*4];
      const float kbr[4] = {kb4.x, kb4.y, kb4.z, kb4.w};
      #pragma unroll
      for (int reg = 0; reg < 4; ++reg) {
        const int kl = cb*16 + lrow*4 + reg;
        const int tc = 15 + kl - lcol;         // [0, 142]
        const float sv = s[cb][reg] + bf2f(Tw[lcol*PADT2 + tc]) + kbr[reg];
        s[cb][reg] = (j0 + kl > ib + lcol) ? -3.0e38f : sv;
      }
    }
    // ---- online softmax (per-q via xor 16/32 over 4 lrow lanes) ----
    float mx = s[0][0];
    #pragma unroll
    for (int cb = 0; cb < 8; ++cb)
      #pragma unroll
      for (int reg = 0; reg < 4; ++reg) mx = fmaxf(mx, s[cb][reg]);
    mx = fmaxf(mx, __shfl_xor(mx, 16, 64));
    mx = fmaxf(mx, __shfl_xor(mx, 32, 64));
    const float mn = fmaxf(mreg, mx);
    const float al = __expf(mreg - mn);
    mreg = mn;
    float ps = 0.f;
    unsigned pk[8][2];
    #pragma unroll
    for (int cb = 0; cb < 8; ++cb) {
      float p0 = __expf(s[cb][0] - mn), p1 = __expf(s[cb][1] - mn);
      float p2 = __expf(s[cb][2] - mn), p3 = __expf(s[cb][3] - mn);
      ps += (p0 + p1) + (p2 + p3);
      pk[cb][0] = cvt_pk_bf16(p0, p1);
      pk[cb][1] = cvt_pk_bf16(p2, p3);
    }
    ps += __shfl_xor(ps, 16, 64);
    ps += __shfl_xor(ps, 32, 64);
    lreg = lreg*al + ps;
    #pragma unroll
    for (int cb = 0; cb < 4; ++cb)            // O^T rescale: al is lane-local (q=lcol)
      #pragma unroll
      for (int reg = 0; reg < 4; ++reg) accO[cb][reg] *= al;
    // ---- P^T B-fragments via shfl; O^T += V^T * P^T (Vtf batched 2+2 ks) --
    const int srcA = ((lrow & 1) << 5) + lcol;
    const int srcB = srcA + 16;
    const bool hi2 = (lrow >> 1) != 0;
    #pragma unroll
    for (int kb = 0; kb < 2; ++kb) {
      short8 vta[2][4];
      #pragma unroll
      for (int ks2 = 0; ks2 < 2; ++ks2)
        #pragma unroll
        for (int cb = 0; cb < 4; ++cb)
          vta[ks2][cb] = *(const short8*)&Vtf[((size_t)((bn*4 + cb)*64 + t*4 + kb*2 + ks2))*512 + lane*8];
      #pragma unroll
      for (int ks2 = 0; ks2 < 2; ++ks2) {
        const int ks = kb*2 + ks2;
        const unsigned a0 = (unsigned)__shfl((int)pk[2*ks  ][0], srcA, 64);
        const unsigned b0 = (unsigned)__shfl((int)pk[2*ks+1][0], srcA, 64);
        const unsigned a1 = (unsigned)__shfl((int)pk[2*ks  ][1], srcA, 64);
        const unsigned b1 = (unsigned)__shfl((int)pk[2*ks+1][1], srcA, 64);
        const unsigned a2 = (unsigned)__shfl((int)pk[2*ks  ][0], srcB, 64);
        const unsigned b2 = (unsigned)__shfl((int)pk[2*ks+1][0], srcB, 64);
        const unsigned a3 = (unsigned)__shfl((int)pk[2*ks  ][1], srcB, 64);
        const unsigned b3 = (unsigned)__shfl((int)pk[2*ks+1][1], srcB, 64);
        i32x4 pw = { (int)(hi2 ? b0 : a0), (int)(hi2 ? b1 : a1),
                     (int)(hi2 ? b2 : a2), (int)(hi2 ? b3 : a3) };
        const short8 pb = __builtin_bit_cast(short8, pw);
        #pragma unroll
        for (int cb = 0; cb < 4; ++cb)
          accO[cb] = __builtin_amdgcn_mfma_f32_16x16x32_bf16(vta[ks2][cb], pb, accO[cb], 0, 0, 0);
      }
    }
  }
  // ---- cross-wave merge in LDS (handles O^T -> O transpose) ----
  __syncthreads();
  float* Macc = (float*)smem;                        // [128][68]: row = wv*16 + q
  float* Mm   = (float*)(smem + 128*68*4);           // [128]
  float* Ml   = Mm + 128;
  #pragma unroll
  for (int cb = 0; cb < 4; ++cb)
    #pragma unroll
    for (int reg = 0; reg < 4; ++reg)
      Macc[(wv*16 + lcol)*68 + cb*16 + lrow*4 + reg] = accO[cb][reg];
  if (lrow == 0) { Mm[wv*16 + lcol] = mreg; Ml[wv*16 + lcol] = lreg; }
  __syncthreads();
  #pragma unroll
  for (int h = 0; h < 2; ++h) {
    const int o = tid + h*512;
    const int row = o >> 6, col = o & 63;            // q-row 0..15, d 0..63
    float M = Mm[row];
    #pragma unroll
    for (int w2 = 1; w2 < 8; ++w2) M = fmaxf(M, Mm[w2*16 + row]);
    float L = 0.f, V = 0.f;
    #pragma unroll
    for (int w2 = 0; w2 < 8; ++w2) {
      const float e = __expf(Mm[w2*16 + row] - M);
      L += Ml[w2*16 + row] * e;
      V += Macc[(w2*16 + row)*68 + col] * e;
    }
    AV[((size_t)bn*QLEN + ib + row)*DH + col] = f2bf(V / L);
  }
}

// ---------------------------------------------------------------------------
// Kernel 6: O-projection, bf16 MFMA; B = o_w f32 (pack fused into staging).
// ---------------------------------------------------------------------------
__global__ __launch_bounds__(256)
void oproj_mfma(const ushort_t* __restrict__ AVp, const float* __restrict__ B,
                float* __restrict__ AO) {
  __shared__ __align__(16) ushort_t As[128*64];
  __shared__ __align__(16) ushort_t Bs[128*64];
  const int bx = blockIdx.x;        // 6 N-tiles
  const int by = blockIdx.y;        // 32 M-tiles
  const int rbase = by*128, cbase = bx*128;
  const int tid = threadIdx.x;
  const int wv = tid>>6, lane = tid&63, lrow = lane>>4, lcol = lane&15;
  const int wr = wv>>1, wc = wv&1;
  const int sr = tid>>3, sc = tid&7;

  f32x4 acc[4][4];
  #pragma unroll
  for (int m = 0; m < 4; ++m)
    #pragma unroll
    for (int nn = 0; nn < 4; ++nn)
      acc[m][nn] = (f32x4){0.f,0.f,0.f,0.f};

  for (int kk = 0; kk < DM; kk += 64) {
    const int nh = kk >> 6;         // head index
    __syncthreads();
    #pragma unroll
    for (int q = 0; q < 4; ++q) {
      const int row = sr + 32*q;
      const int r = rbase + row, i = r >> 1, b = r & 1;
      const short8 va = *(const short8*)&AVp[((size_t)(b*NH + nh)*QLEN + i)*DH + sc*8];
      *(short8*)((char*)As + row*128 + ((sc*16) ^ ((row&7)<<4))) = va;
      const float4 b0 = *(const float4*)&B[(size_t)(cbase+row)*DM + kk + sc*8];
      const float4 b1 = *(const float4*)&B[(size_t)(cbase+row)*DM + kk + sc*8 + 4];
      i32x4 vb = { (int)cvt_pk_bf16(b0.x,b0.y), (int)cvt_pk_bf16(b0.z,b0.w),
                   (int)cvt_pk_bf16(b1.x,b1.y), (int)cvt_pk_bf16(b1.z,b1.w) };
      *(short8*)((char*)Bs + row*128 + ((sc*16) ^ ((row&7)<<4))) = __builtin_bit_cast(short8, vb);
    }
    __syncthreads();
    short8 af[4][2], bfr[4][2];
    #pragma unroll
    for (int m = 0; m < 4; ++m) {
      const int row = wr*64 + m*16 + lcol;
      af[m][0] = *(const short8*)((const char*)As + row*128 + (((     lrow*16)) ^ ((row&7)<<4)));
      af[m][1] = *(const short8*)((const char*)As + row*128 + (((64 + lrow*16)) ^ ((row&7)<<4)));
    }
    #pragma unroll
    for (int nn = 0; nn < 4; ++nn) {
      const int row = wc*64 + nn*16 + lcol;
      bfr[nn][0] = *(const short8*)((const char*)Bs + row*128 + (((     lrow*16)) ^ ((row&7)<<4)));
      bfr[nn][1] = *(const short8*)((const char*)Bs + row*128 + (((64 + lrow*16)) ^ ((row&7)<<4)));
    }
    #pragma unroll
    for (int m = 0; m < 4; ++m)
      #pragma unroll
      for (int nn = 0; nn < 4; ++nn) {
        acc[m][nn] = __builtin_amdgcn_mfma_f32_16x16x32_bf16(af[m][0], bfr[nn][0], acc[m][nn], 0, 0, 0);
        acc[m][nn] = __builtin_amdgcn_mfma_f32_16x16x32_bf16(af[m][1], bfr[nn][1], acc[m][nn], 0, 0, 0);
      }
  }
  #pragma unroll
  for (int nn = 0; nn < 4; ++nn) {
    const int mcol = cbase + wc*64 + nn*16 + lcol;
    #pragma unroll
    for (int mi = 0; mi < 4; ++mi)
      #pragma unroll
      for (int reg = 0; reg < 4; ++reg) {
        const int r = rbase + wr*64 + mi*16 + lrow*4 + reg;
        AO[(size_t)r*DM + mcol] = acc[mi][nn][reg];
      }
  }
}

// ---------------------------------------------------------------------------
// Kernel 7: residual + LayerNorm.
// ---------------------------------------------------------------------------
__global__ __launch_bounds__(256)
void ln_kernel(const float* __restrict__ AO, const float* __restrict__ W,
               const float* __restrict__ gamma, const float* __restrict__ beta,
               float* __restrict__ out) {
  const int r = blockIdx.x;
  const int tid = threadIdx.x;
  const int wv = tid >> 6, lane = tid & 63;
  float x[3];
  #pragma unroll
  for (int q = 0; q < 3; ++q) {
    const int mcol = tid + q*256;
    x[q] = AO[(size_t)r*DM + mcol] + W[(size_t)r*DM + mcol];
  }
  float s1 = x[0] + x[1] + x[2];
  float s2 = x[0]*x[0] + x[1]*x[1] + x[2]*x[2];
  #pragma unroll
  for (int o = 32; o > 0; o >>= 1) { s1 += __shfl_xor(s1, o, 64); s2 += __shfl_xor(s2, o, 64); }
  __shared__ float a1[4], a2[4];
  if (lane == 0) { a1[wv] = s1; a2[wv] = s2; }
  __syncthreads();
  s1 = a1[0] + a1[1] + a1[2] + a1[3];
  s2 = a2[0] + a2[1] + a2[2] + a2[3];
  const float mu  = s1 * (1.0f/DM);
  const float var = s2 * (1.0f/DM) - mu*mu;
  const float rs  = rsqrtf(var + 1e-5f);
  #pragma unroll
  for (int q = 0; q < 3; ++q) {
    const int mcol = tid + q*256;
    out[(size_t)r*DM + mcol] = (x[q] - mu)*rs*gamma[mcol] + beta[mcol];
  }
}

// ---------------------------------------------------------------------------
extern "C" void kernel_launch(void* const* d_in, const int* in_sizes, int n_in,
                              void* d_out, int out_size, void* d_ws, size_t ws_size,
                              hipStream_t stream) {
  const float* w      = (const float*)d_in[0];
  const float* r_emb  = (const float*)d_in[1];
  const float* r_wb   = (const float*)d_in[2];
  const float* r_bias = (const float*)d_in[3];
  const float* qkv_w  = (const float*)d_in[4];
  const float* o_w    = (const float*)d_in[5];
  const float* ln_g   = (const float*)d_in[6];
  const float* ln_b   = (const float*)d_in[7];
  float* out = (float*)d_out;

  const size_t QS = (size_t)BSZ*NH*QLEN*DH;       // 3,145,728 elems
  ushort_t* u     = (ushort_t*)d_ws;
  ushort_t* Vb16  = u;                            // QS (dead after vt_pack)
  ushort_t* AVb16 = Vb16;                         // overlay: written by attn
  ushort_t* Qfb   = u + QS;
  ushort_t* Kfb   = Qfb + QS;
  ushort_t* Vtf   = Kfb + QS;
  ushort_t* RELf  = Vtf + QS;                     // NH*RELROWS*DH
  float* rbp = (float*)(RELf + (size_t)NH*RELROWS*DH);
  float* KBb = rbp + NH*RELROWS;                  // 49152 f32
  float* AO  = (float*)Qfb;                       // overlays Qf+Kf (dead by oproj)

  qkv_mfma<<<dim3(HID/128, (QLEN*BSZ)/128), dim3(256), 0, stream>>>(w, qkv_w, Qfb, Kfb, Vb16);
  vt_pack<<<dim3(QLEN/64, BSZ*NH), dim3(256), 0, stream>>>(Vb16, Vtf);
  rel_pack<<<dim3(RELROWS/4, NH), dim3(256), 0, stream>>>(r_emb, r_bias, RELf, rbp);
  kbias_kernel<<<dim3(BSZ*NH*QLEN/4), dim3(256), 0, stream>>>(Kfb, r_wb, KBb);
  attn_kernel<<<dim3(3072), dim3(512), 0, stream>>>(Qfb, Kfb, Vtf, RELf, rbp, KBb, AVb16);
  oproj_mfma<<<dim3(DM/128, (QLEN*BSZ)/128), dim3(256), 0, stream>>>(AVb16, o_w, AO);
  ln_kernel<<<dim3(QLEN*BSZ), dim3(256), 0, stream>>>(AO, w, ln_g, ln_b, out);
}